// Round 4
// baseline (3805.754 us; speedup 1.0000x reference)
//
#include <hip/hip_runtime.h>
#include <stdint.h>

#define B_ 16384
#define S_ 336
#define T_ 48
#define IN_ 5
#define H_ 64

#define ROWS 32      // batch rows per block
#define GP   256     // f16 stride per g-group = ROWS*8

typedef _Float16 f16;
typedef _Float16 f16x8 __attribute__((ext_vector_type(8)));
typedef float f32x4 __attribute__((ext_vector_type(4)));

#define LOG2E 1.44269504088896340736f

// ---- ws layout (float words) ---- (geometry unchanged; pl=1 planes unused now)
// A-fragment packed weights: [mt16][kt][lane64][pl2][reg4] u32 words
// Weights & biases PRE-SCALED: gate rows i,f,o by -log2e, gate g by +2*log2e.
// L0 x-chunk slot k==5 carries the L0 bias (bih+bhh); B-side stages 1.0 there.
#define OFF_E0 0
#define OFF_E1 24576
#define OFF_D0 57344
#define OFF_D1 81920
#define OFF_BE0 114688
#define OFF_BE1 114944
#define OFF_BD0 115200
#define OFF_BD1 115456
#define OFF_FCW 115712
#define OFF_FCB 115776
#define WS_TOT  115777

__device__ __forceinline__ float sig2(float g) {     // sigmoid(z), g = -log2e*z
    return __builtin_amdgcn_rcpf(1.0f + __builtin_amdgcn_exp2f(g));
}
__device__ __forceinline__ float tanh2(float g) {    // tanh(z), g = 2*log2e*z
    return 1.0f - 2.0f * __builtin_amdgcn_rcpf(1.0f + __builtin_amdgcn_exp2f(g));
}
__device__ __forceinline__ float tanhc(float c) {    // tanh(c), raw c
    return 1.0f - 2.0f * __builtin_amdgcn_rcpf(1.0f + __builtin_amdgcn_exp2f(c * (2.0f * LOG2E)));
}

// ---------------- prep: pack weights into MFMA A-fragment layout ----
__global__ void prep_kernel(
    const float* __restrict__ eWih0, const float* __restrict__ eWhh0,
    const float* __restrict__ ebih0, const float* __restrict__ ebhh0,
    const float* __restrict__ eWih1, const float* __restrict__ eWhh1,
    const float* __restrict__ ebih1, const float* __restrict__ ebhh1,
    const float* __restrict__ dWih0, const float* __restrict__ dWhh0,
    const float* __restrict__ dbih0, const float* __restrict__ dbhh0,
    const float* __restrict__ dWih1, const float* __restrict__ dWhh1,
    const float* __restrict__ dbih1, const float* __restrict__ dbhh1,
    const float* __restrict__ fcW,  const float* __restrict__ fcb,
    float* __restrict__ ws)
{
    int idx = blockIdx.x * blockDim.x + threadIdx.x;
    if (idx >= WS_TOT) return;
    float outv;
    if (idx < OFF_BE0) {
        int rel, nkt, xdim;
        const float *Wi, *Wh, *bi, *bh;
        if (idx < OFF_E1)      { rel = idx - OFF_E0; nkt = 3; xdim = IN_; Wi = eWih0; Wh = eWhh0; bi = ebih0; bh = ebhh0; }
        else if (idx < OFF_D0) { rel = idx - OFF_E1; nkt = 4; xdim = 64;  Wi = eWih1; Wh = eWhh1; bi = 0; bh = 0; }
        else if (idx < OFF_D1) { rel = idx - OFF_D0; nkt = 3; xdim = 1;   Wi = dWih0; Wh = dWhh0; bi = dbih0; bh = dbhh0; }
        else                   { rel = idx - OFF_D1; nkt = 4; xdim = 64;  Wi = dWih1; Wh = dWhh1; bi = 0; bh = 0; }
        int reg = rel & 3, pl = (rel >> 2) & 1, lane = (rel >> 3) & 63;
        int rest = rel >> 9;
        int kt = rest % nkt, mt = rest / nkt;
        int gp = mt * 16 + (lane & 15);
        int type = gp & 3;
        int j  = type * 64 + (gp >> 2);
        float sc = (type == 2) ? (2.0f * LOG2E) : (-LOG2E);
        union { f16 h2[2]; float f; } u_;
        #pragma unroll
        for (int h = 0; h < 2; ++h) {
            int k = kt * 32 + (lane >> 4) * 8 + reg * 2 + h;
            float v;
            if (nkt == 4)      v = (k < 64) ? Wi[j * 64 + k] : Wh[j * 64 + (k - 64)];
            else if (k < xdim) v = Wi[j * xdim + k];
            else if (k == 5)   v = bi[j] + bh[j];      // L0 bias in slot 5
            else if (k >= 32)  v = Wh[j * 64 + (k - 32)];
            else               v = 0.0f;
            v *= sc;
            f16 hi = (f16)v;
            u_.h2[h] = (pl == 0) ? hi : (f16)(v - (float)hi);
        }
        outv = u_.f;
    } else if (idx < OFF_FCW) {
        int rel = idx - OFF_BE0;
        int which = rel >> 8, gp = rel & 255;
        int type = gp & 3;
        int j = type * 64 + (gp >> 2);
        float sc = (type == 2) ? (2.0f * LOG2E) : (-LOG2E);
        const float *bi, *bh;
        if (which == 0)      { bi = ebih0; bh = ebhh0; }
        else if (which == 1) { bi = ebih1; bh = ebhh1; }
        else if (which == 2) { bi = dbih0; bh = dbhh0; }
        else                 { bi = dbih1; bh = dbhh1; }
        outv = (bi[j] + bh[j]) * sc;
    } else if (idx < OFF_FCB) {
        outv = fcW[idx - OFF_FCW];
    } else {
        outv = fcb[0];
    }
    ws[idx] = outv;
}

// LDS index helpers (f16 element index), ROWS=32 geometry
#define XBI(b,p,g,r)   ((((b)*2+(p))*4+(g))*GP + (r)*8)
#define HBI(b,p,k,g,r) (((((b)*2+(p))*2+(k))*4+(g))*GP + (r)*8)

#define MFMA(a,b,c) __builtin_amdgcn_mfma_f32_16x16x32_f16(a, b, c, 0, 0, 0)

__device__ __forceinline__ void stage_x5(f16* __restrict__ XB, int b, int r, const float* xv) {
    f16x8 ph, pl_;
    #pragma unroll
    for (int i = 0; i < 8; ++i) { ph[i] = (f16)0; pl_[i] = (f16)0; }
    #pragma unroll
    for (int i = 0; i < IN_; ++i) {
        f16 hh = (f16)xv[i]; ph[i] = hh; pl_[i] = (f16)(xv[i] - (float)hh);
    }
    ph[5] = (f16)1.0f;          // bias slot
    *(f16x8*)&XB[XBI(b,0,0,r)] = ph;
    *(f16x8*)&XB[XBI(b,1,0,r)] = pl_;
}
__device__ __forceinline__ void stage_x1(f16* __restrict__ XB, int b, int r, float v) {
    f16x8 ph, pl_;
    #pragma unroll
    for (int i = 0; i < 8; ++i) { ph[i] = (f16)0; pl_[i] = (f16)0; }
    f16 hh = (f16)v; ph[0] = hh; pl_[0] = (f16)(v - (float)hh);
    ph[5] = (f16)1.0f;          // bias slot
    *(f16x8*)&XB[XBI(b,0,0,r)] = ph;
    *(f16x8*)&XB[XBI(b,1,0,r)] = pl_;
}

// ---- standalone layer 0 (prologue + decoder): acc starts at 0 (bias in slot 5)
__device__ __forceinline__ void layer0_only(
    int pX, int pH0r, int pH0w, int m0, int lane,
    const f16x8 (&wa)[7][2], float (&c0)[2][2],
    const f16* __restrict__ XB, f16* __restrict__ H0B)
{
    const int g4 = lane >> 4, l15 = lane & 15;
    #pragma unroll
    for (int nt = 0; nt < 2; ++nt) {
        const int r = nt * 16 + l15;
        f16x8 xh  = *(const f16x8*)&XB [XBI(pX,0,g4,r)];
        f16x8 xl  = *(const f16x8*)&XB [XBI(pX,1,g4,r)];
        f16x8 hh0 = *(const f16x8*)&H0B[HBI(pH0r,0,0,g4,r)];
        f16x8 hl0 = *(const f16x8*)&H0B[HBI(pH0r,1,0,g4,r)];
        f16x8 hh1 = *(const f16x8*)&H0B[HBI(pH0r,0,1,g4,r)];
        f16x8 hl1 = *(const f16x8*)&H0B[HBI(pH0r,1,1,g4,r)];
        #pragma unroll
        for (int mt = 0; mt < 2; ++mt) {
            f32x4 z = {0.0f, 0.0f, 0.0f, 0.0f};
            z = MFMA(wa[0][mt], xh,  z);
            z = MFMA(wa[0][mt], xl,  z);
            z = MFMA(wa[1][mt], hh0, z);
            z = MFMA(wa[1][mt], hl0, z);
            z = MFMA(wa[2][mt], hh1, z);
            z = MFMA(wa[2][mt], hl1, z);
            const int u = (m0 + mt) * 4 + g4;
            float ig = sig2(z[0]), fg = sig2(z[1]);
            float gg = tanh2(z[2]), og = sig2(z[3]);
            float c = fmaf(fg, c0[mt][nt], ig * gg);
            c0[mt][nt] = c;
            float h = og * tanhc(c);
            f16 hh = (f16)h, hl = (f16)(h - (float)hh);
            H0B[HBI(pH0w,0,(u>>5),(u>>3)&3,r) + (u&7)] = hh;
            H0B[HBI(pH0w,1,(u>>5),(u>>3)&3,r) + (u&7)] = hl;
        }
    }
}

// ---- standalone layer 1 (epilogue + decoder)
template<bool DEC>
__device__ __forceinline__ void layer1_only(
    int pH0, int pH1r, int pH1w, int m0, int lane,
    const f16x8 (&wa)[7][2], const f32x4 (&b1)[2], float (&c1)[2][2],
    const f16* __restrict__ H0B, f16* __restrict__ H1B, float* __restrict__ H1F)
{
    const int g4 = lane >> 4, l15 = lane & 15;
    #pragma unroll
    for (int nt = 0; nt < 2; ++nt) {
        const int r = nt * 16 + l15;
        f16x8 hh0 = *(const f16x8*)&H0B[HBI(pH0,0,0,g4,r)];
        f16x8 hl0 = *(const f16x8*)&H0B[HBI(pH0,1,0,g4,r)];
        f16x8 hh1 = *(const f16x8*)&H0B[HBI(pH0,0,1,g4,r)];
        f16x8 hl1 = *(const f16x8*)&H0B[HBI(pH0,1,1,g4,r)];
        f16x8 gh0 = *(const f16x8*)&H1B[HBI(pH1r,0,0,g4,r)];
        f16x8 gl0 = *(const f16x8*)&H1B[HBI(pH1r,1,0,g4,r)];
        f16x8 gh1 = *(const f16x8*)&H1B[HBI(pH1r,0,1,g4,r)];
        f16x8 gl1 = *(const f16x8*)&H1B[HBI(pH1r,1,1,g4,r)];
        #pragma unroll
        for (int mt = 0; mt < 2; ++mt) {
            f32x4 a = b1[mt];
            a = MFMA(wa[3][mt], hh0, a);
            a = MFMA(wa[3][mt], hl0, a);
            a = MFMA(wa[4][mt], hh1, a);
            a = MFMA(wa[4][mt], hl1, a);
            a = MFMA(wa[5][mt], gh0, a);
            a = MFMA(wa[5][mt], gl0, a);
            a = MFMA(wa[6][mt], gh1, a);
            a = MFMA(wa[6][mt], gl1, a);
            const int u = (m0 + mt) * 4 + g4;
            float ig = sig2(a[0]), fg = sig2(a[1]);
            float gg = tanh2(a[2]), og = sig2(a[3]);
            float c = fmaf(fg, c1[mt][nt], ig * gg);
            c1[mt][nt] = c;
            float h = og * tanhc(c);
            f16 hh = (f16)h, hl = (f16)(h - (float)hh);
            H1B[HBI(pH1w,0,(u>>5),(u>>3)&3,r) + (u&7)] = hh;
            H1B[HBI(pH1w,1,(u>>5),(u>>3)&3,r) + (u&7)] = hl;
            if (DEC) H1F[u * 33 + r] = h;
        }
    }
}

// ---- fused encoder phase t: {L1_t ; L0_{t+1}} — ONE barrier per timestep.
__device__ __forceinline__ void enc_phase(
    int p, int m0, int lane,
    const f16x8 (&wa)[7][2], const f32x4 (&b1)[2],
    float (&c0)[2][2], float (&c1)[2][2],
    const f16* __restrict__ XB, f16* __restrict__ H0B, f16* __restrict__ H1B)
{
    const int g4 = lane >> 4, l15 = lane & 15;
    const int q = p ^ 1;
    #pragma unroll
    for (int nt = 0; nt < 2; ++nt) {
        const int r = nt * 16 + l15;
        f16x8 hh0 = *(const f16x8*)&H0B[HBI(p,0,0,g4,r)];   // h0_t (shared L1/L0)
        f16x8 hl0 = *(const f16x8*)&H0B[HBI(p,1,0,g4,r)];
        f16x8 hh1 = *(const f16x8*)&H0B[HBI(p,0,1,g4,r)];
        f16x8 hl1 = *(const f16x8*)&H0B[HBI(p,1,1,g4,r)];
        f16x8 gh0 = *(const f16x8*)&H1B[HBI(q,0,0,g4,r)];   // h1_{t-1}
        f16x8 gl0 = *(const f16x8*)&H1B[HBI(q,1,0,g4,r)];
        f16x8 gh1 = *(const f16x8*)&H1B[HBI(q,0,1,g4,r)];
        f16x8 gl1 = *(const f16x8*)&H1B[HBI(q,1,1,g4,r)];
        // ---- L1_t ----
        #pragma unroll
        for (int mt = 0; mt < 2; ++mt) {
            const int u = (m0 + mt) * 4 + g4;
            f32x4 a = b1[mt];
            a = MFMA(wa[3][mt], hh0, a);
            a = MFMA(wa[3][mt], hl0, a);
            a = MFMA(wa[4][mt], hh1, a);
            a = MFMA(wa[4][mt], hl1, a);
            a = MFMA(wa[5][mt], gh0, a);
            a = MFMA(wa[5][mt], gl0, a);
            a = MFMA(wa[6][mt], gh1, a);
            a = MFMA(wa[6][mt], gl1, a);
            float ig = sig2(a[0]), fg = sig2(a[1]);
            float gg = tanh2(a[2]), og = sig2(a[3]);
            float c = fmaf(fg, c1[mt][nt], ig * gg);
            c1[mt][nt] = c;
            float h = og * tanhc(c);
            f16 hh = (f16)h, hl = (f16)(h - (float)hh);
            H1B[HBI(p,0,(u>>5),(u>>3)&3,r) + (u&7)] = hh;
            H1B[HBI(p,1,(u>>5),(u>>3)&3,r) + (u&7)] = hl;
        }
        // ---- L0_{t+1} ----
        f16x8 xh = *(const f16x8*)&XB[XBI(q,0,g4,r)];       // x_{t+1}
        f16x8 xl = *(const f16x8*)&XB[XBI(q,1,g4,r)];
        #pragma unroll
        for (int mt = 0; mt < 2; ++mt) {
            const int u = (m0 + mt) * 4 + g4;
            f32x4 z = {0.0f, 0.0f, 0.0f, 0.0f};
            z = MFMA(wa[0][mt], xh,  z);
            z = MFMA(wa[0][mt], xl,  z);
            z = MFMA(wa[1][mt], hh0, z);
            z = MFMA(wa[1][mt], hl0, z);
            z = MFMA(wa[2][mt], hh1, z);
            z = MFMA(wa[2][mt], hl1, z);
            float ig = sig2(z[0]), fg = sig2(z[1]);
            float gg = tanh2(z[2]), og = sig2(z[3]);
            float c = fmaf(fg, c0[mt][nt], ig * gg);
            c0[mt][nt] = c;
            float h = og * tanhc(c);
            f16 hh = (f16)h, hl = (f16)(h - (float)hh);
            H0B[HBI(q,0,(u>>5),(u>>3)&3,r) + (u&7)] = hh;
            H0B[HBI(q,1,(u>>5),(u>>3)&3,r) + (u&7)] = hl;
        }
    }
}

// 512 threads = 8 waves; wave w owns M-tiles {2w,2w+1} (units 8w..8w+7);
// 32 batch rows/block; grid = 512 -> 2 blocks/CU (anti-phase overlap).
// 2-term scheme: W f16 (single plane, 56 VGPR), h staged hi/lo.
// waves_per_eu(4): cap 128 VGPR so 2 blocks (16 waves) fit per CU.
__global__ __launch_bounds__(512)
__attribute__((amdgpu_waves_per_eu(4)))
void lstm_kernel(
    const float* __restrict__ src, const float* __restrict__ ws,
    float* __restrict__ out)
{
    __shared__ __align__(16) f16 XB [2*2*4*GP];       // 8 KB
    __shared__ __align__(16) f16 H0B[2*2*2*4*GP];     // 16 KB
    __shared__ __align__(16) f16 H1B[2*2*2*4*GP];     // 16 KB
    __shared__ float H1F[64*33];                      // 8.25 KB (decoder fc)
    __shared__ float FCW[64];

    const int tid  = threadIdx.x;
    const int lane = tid & 63;
    const int wave = __builtin_amdgcn_readfirstlane(tid >> 6);
    const int m0   = wave * 2;
    const int g4   = lane >> 4;
    const int rowBase = blockIdx.x * ROWS;

    float c0[2][2], c1[2][2];
    #pragma unroll
    for (int mt = 0; mt < 2; ++mt)
        #pragma unroll
        for (int nt = 0; nt < 2; ++nt) { c0[mt][nt] = 0.0f; c1[mt][nt] = 0.0f; }

    f16x8 wa[7][2];             // [kt: 0-2 L0, 3-6 L1][mt], hi plane only
    f32x4 b1[2];

    auto ldw = [&](int off0, int off1, int ob1) {
        #pragma unroll
        for (int kt = 0; kt < 3; ++kt)
            #pragma unroll
            for (int mt = 0; mt < 2; ++mt)
                wa[kt][mt] = *(const f16x8*)(ws + off0 +
                    ((((m0 + mt) * 3 + kt) * 64 + lane) * 2) * 4);
        #pragma unroll
        for (int kt = 0; kt < 4; ++kt)
            #pragma unroll
            for (int mt = 0; mt < 2; ++mt)
                wa[3 + kt][mt] = *(const f16x8*)(ws + off1 +
                    ((((m0 + mt) * 4 + kt) * 64 + lane) * 2) * 4);
        #pragma unroll
        for (int mt = 0; mt < 2; ++mt)
            b1[mt] = *(const f32x4*)(ws + ob1 + (m0 + mt) * 16 + g4 * 4);
    };
    ldw(OFF_E0, OFF_E1, OFF_BE1);

    // zero all LDS state buffers (h_{-1} = 0, x pads = 0)
    for (int i = tid; i < 2*2*4*GP; i += 512) XB[i] = (f16)0;
    for (int i = tid; i < 2*2*2*4*GP; i += 512) { H0B[i] = (f16)0; H1B[i] = (f16)0; }
    if (tid < 64) FCW[tid] = ws[OFF_FCW + tid];
    const float fcbv = ws[OFF_FCB];

    const int xr = lane & (ROWS - 1);
    const float* sp = src + (size_t)(rowBase + xr) * (S_ * IN_);
    __syncthreads();

    // stage x0 -> XB[0], x1 -> XB[1]
    if (wave == 7 && lane < ROWS) {
        float xv[IN_];
        #pragma unroll
        for (int i = 0; i < IN_; ++i) xv[i] = sp[i];
        stage_x5(XB, 0, lane, xv);
        #pragma unroll
        for (int i = 0; i < IN_; ++i) xv[i] = sp[IN_ + i];
        stage_x5(XB, 1, lane, xv);
    }
    __syncthreads();

    // prologue: L0_0 (reads XB[0], H0B[1](=0), writes H0B[0])
    layer0_only(0, 1, 0, m0, lane, wa, c0, XB, H0B);
    __syncthreads();

    // ---------------- encoder: fused phases, ONE barrier per timestep ----------
    #pragma unroll 1
    for (int t = 0; t < S_ - 1; ++t) {
        const int p = t & 1;
        float xv[IN_];
        const bool pf = (wave == 7) && (lane < ROWS) && (t + 2 < S_);
        if (pf) {
            #pragma unroll
            for (int i = 0; i < IN_; ++i) xv[i] = sp[(t + 2) * IN_ + i];
        }
        enc_phase(p, m0, lane, wa, b1, c0, c1, XB, H0B, H1B);
        if (pf) stage_x5(XB, p, lane, xv);   // x_{t+2} -> XB[p]
        __syncthreads();
    }

    // epilogue: L1_{S-1} (reads H0B[1], H1B[0], writes H1B[1])
    layer1_only<false>(1, 0, 1, m0, lane, wa, b1, c1, H0B, H1B, H1F);
    __syncthreads();

    // ---------------- decoder ----------------
    ldw(OFF_D0, OFF_D1, OFF_BD1);
    if (wave == 7 && lane < ROWS) stage_x1(XB, 0, lane, sp[(S_ - 1) * IN_ + 3]);
    __syncthreads();

    #pragma unroll 1
    for (int t = 0; t < T_; ++t) {
        const int q = t & 1;
        layer0_only(q, q ^ 1, q, m0, lane, wa, c0, XB, H0B);
        __syncthreads();
        layer1_only<true>(q, q ^ 1, q, m0, lane, wa, b1, c1, H0B, H1B, H1F);
        __syncthreads();
        if (wave == 0 && lane < ROWS) {   // fc head (lane = row)
            float pv = fcbv;
            #pragma unroll 4
            for (int k = 0; k < 64; ++k) pv = fmaf(FCW[k], H1F[k * 33 + lane], pv);
            out[(size_t)(rowBase + lane) * T_ + t] = pv;
            if (t + 1 < T_) stage_x1(XB, q ^ 1, lane, pv);
        }
        __syncthreads();
    }
}

extern "C" void kernel_launch(void* const* d_in, const int* in_sizes, int n_in,
                              void* d_out, int out_size, void* d_ws, size_t ws_size,
                              hipStream_t stream)
{
    const float* src = (const float*)d_in[0];
    float* ws  = (float*)d_ws;
    float* out = (float*)d_out;

    prep_kernel<<<(WS_TOT + 255) / 256, 256, 0, stream>>>(
        (const float*)d_in[1],  (const float*)d_in[2],
        (const float*)d_in[3],  (const float*)d_in[4],
        (const float*)d_in[5],  (const float*)d_in[6],
        (const float*)d_in[7],  (const float*)d_in[8],
        (const float*)d_in[9],  (const float*)d_in[10],
        (const float*)d_in[11], (const float*)d_in[12],
        (const float*)d_in[13], (const float*)d_in[14],
        (const float*)d_in[15], (const float*)d_in[16],
        (const float*)d_in[17], (const float*)d_in[18],
        ws);

    lstm_kernel<<<B_ / ROWS, 512, 0, stream>>>(src, ws, out);
}

// Round 5
// 1745.674 us; speedup vs baseline: 2.1801x; 2.1801x over previous
//
#include <hip/hip_runtime.h>
#include <stdint.h>

#define B_ 16384
#define S_ 336
#define T_ 48
#define IN_ 5
#define H_ 64

typedef _Float16 f16;
typedef _Float16 f16x8 __attribute__((ext_vector_type(8)));
typedef float f32x4 __attribute__((ext_vector_type(4)));

#define LOG2E 1.44269504088896340736f

// ---- ws layout (float words) ----
// A-fragment packed weights: [mt16][kt][lane64][pl2][reg4] u32 words (pl=1 unused)
// Weights & biases PRE-SCALED: gate rows i,f,o by -log2e, gate g by +2*log2e.
// L0 x-chunk slot k==5 carries the L0 bias (bih+bhh); B-side stages 1.0 there.
#define OFF_E0 0
#define OFF_E1 24576
#define OFF_D0 57344
#define OFF_D1 81920
#define OFF_BE0 114688
#define OFF_BE1 114944
#define OFF_BD0 115200
#define OFF_BD1 115456
#define OFF_FCW 115712
#define OFF_FCB 115776
#define WS_TOT  115777

__device__ __forceinline__ float sig2(float g) {     // sigmoid(z), g = -log2e*z
    return __builtin_amdgcn_rcpf(1.0f + __builtin_amdgcn_exp2f(g));
}
__device__ __forceinline__ float tanh2(float g) {    // tanh(z), g = 2*log2e*z
    return 1.0f - 2.0f * __builtin_amdgcn_rcpf(1.0f + __builtin_amdgcn_exp2f(g));
}
__device__ __forceinline__ float tanhc(float c) {    // tanh(c), raw c
    return 1.0f - 2.0f * __builtin_amdgcn_rcpf(1.0f + __builtin_amdgcn_exp2f(c * (2.0f * LOG2E)));
}

// ---------------- prep: pack weights into MFMA A-fragment layout ----
__global__ void prep_kernel(
    const float* __restrict__ eWih0, const float* __restrict__ eWhh0,
    const float* __restrict__ ebih0, const float* __restrict__ ebhh0,
    const float* __restrict__ eWih1, const float* __restrict__ eWhh1,
    const float* __restrict__ ebih1, const float* __restrict__ ebhh1,
    const float* __restrict__ dWih0, const float* __restrict__ dWhh0,
    const float* __restrict__ dbih0, const float* __restrict__ dbhh0,
    const float* __restrict__ dWih1, const float* __restrict__ dWhh1,
    const float* __restrict__ dbih1, const float* __restrict__ dbhh1,
    const float* __restrict__ fcW,  const float* __restrict__ fcb,
    float* __restrict__ ws)
{
    int idx = blockIdx.x * blockDim.x + threadIdx.x;
    if (idx >= WS_TOT) return;
    float outv;
    if (idx < OFF_BE0) {
        int rel, nkt, xdim;
        const float *Wi, *Wh, *bi, *bh;
        if (idx < OFF_E1)      { rel = idx - OFF_E0; nkt = 3; xdim = IN_; Wi = eWih0; Wh = eWhh0; bi = ebih0; bh = ebhh0; }
        else if (idx < OFF_D0) { rel = idx - OFF_E1; nkt = 4; xdim = 64;  Wi = eWih1; Wh = eWhh1; bi = 0; bh = 0; }
        else if (idx < OFF_D1) { rel = idx - OFF_D0; nkt = 3; xdim = 1;   Wi = dWih0; Wh = dWhh0; bi = dbih0; bh = dbhh0; }
        else                   { rel = idx - OFF_D1; nkt = 4; xdim = 64;  Wi = dWih1; Wh = dWhh1; bi = 0; bh = 0; }
        int reg = rel & 3, pl = (rel >> 2) & 1, lane = (rel >> 3) & 63;
        int rest = rel >> 9;
        int kt = rest % nkt, mt = rest / nkt;
        int gp = mt * 16 + (lane & 15);
        int type = gp & 3;
        int j  = type * 64 + (gp >> 2);
        float sc = (type == 2) ? (2.0f * LOG2E) : (-LOG2E);
        union { f16 h2[2]; float f; } u_;
        #pragma unroll
        for (int h = 0; h < 2; ++h) {
            int k = kt * 32 + (lane >> 4) * 8 + reg * 2 + h;
            float v;
            if (nkt == 4)      v = (k < 64) ? Wi[j * 64 + k] : Wh[j * 64 + (k - 64)];
            else if (k < xdim) v = Wi[j * xdim + k];
            else if (k == 5)   v = bi[j] + bh[j];      // L0 bias in slot 5
            else if (k >= 32)  v = Wh[j * 64 + (k - 32)];
            else               v = 0.0f;
            v *= sc;
            f16 hi = (f16)v;
            u_.h2[h] = (pl == 0) ? hi : (f16)(v - (float)hi);
        }
        outv = u_.f;
    } else if (idx < OFF_FCW) {
        int rel = idx - OFF_BE0;
        int which = rel >> 8, gp = rel & 255;
        int type = gp & 3;
        int j = type * 64 + (gp >> 2);
        float sc = (type == 2) ? (2.0f * LOG2E) : (-LOG2E);
        const float *bi, *bh;
        if (which == 0)      { bi = ebih0; bh = ebhh0; }
        else if (which == 1) { bi = ebih1; bh = ebhh1; }
        else if (which == 2) { bi = dbih0; bh = dbhh0; }
        else                 { bi = dbih1; bh = dbhh1; }
        outv = (bi[j] + bh[j]) * sc;
    } else if (idx < OFF_FCB) {
        outv = fcW[idx - OFF_FCW];
    } else {
        outv = fcb[0];
    }
    ws[idx] = outv;
}

// LDS index helpers (f16 element index), ROWS=64
#define XBI(b,p,g,r)   ((((((b)*2)+(p))*4+(g))*64+(r))*8)
#define HBI(b,p,k,g,r) (((((((b)*2)+(p))*2+(k))*4+(g))*64+(r))*8)

#define MFMA(a,b,c) __builtin_amdgcn_mfma_f32_16x16x32_f16(a, b, c, 0, 0, 0)

__device__ __forceinline__ void stage_x5(f16* __restrict__ XB, int b, int lane, const float* xv) {
    f16x8 ph, pl_;
    #pragma unroll
    for (int i = 0; i < 8; ++i) { ph[i] = (f16)0; pl_[i] = (f16)0; }
    #pragma unroll
    for (int i = 0; i < IN_; ++i) {
        f16 hh = (f16)xv[i]; ph[i] = hh; pl_[i] = (f16)(xv[i] - (float)hh);
    }
    ph[5] = (f16)1.0f;          // bias slot
    *(f16x8*)&XB[XBI(b,0,0,lane)] = ph;
    *(f16x8*)&XB[XBI(b,1,0,lane)] = pl_;
}
__device__ __forceinline__ void stage_x1(f16* __restrict__ XB, int b, int lane, float v) {
    f16x8 ph, pl_;
    #pragma unroll
    for (int i = 0; i < 8; ++i) { ph[i] = (f16)0; pl_[i] = (f16)0; }
    f16 hh = (f16)v; ph[0] = hh; pl_[0] = (f16)(v - (float)hh);
    ph[5] = (f16)1.0f;          // bias slot
    *(f16x8*)&XB[XBI(b,0,0,lane)] = ph;
    *(f16x8*)&XB[XBI(b,1,0,lane)] = pl_;
}

// ---- standalone layer 0 (prologue + decoder): acc starts at 0 (bias in slot 5)
__device__ __forceinline__ void layer0_only(
    int pX, int pH0r, int pH0w, int m0, int lane,
    const f16x8 (&wa)[7][2], float (&c0)[2][4],
    const f16* __restrict__ XB, f16* __restrict__ H0B)
{
    const int g4 = lane >> 4, l15 = lane & 15;
    #pragma unroll
    for (int nt = 0; nt < 4; ++nt) {
        const int r = nt * 16 + l15;
        f16x8 xh  = *(const f16x8*)&XB [XBI(pX,0,g4,r)];
        f16x8 xl  = *(const f16x8*)&XB [XBI(pX,1,g4,r)];
        f16x8 hh0 = *(const f16x8*)&H0B[HBI(pH0r,0,0,g4,r)];
        f16x8 hl0 = *(const f16x8*)&H0B[HBI(pH0r,1,0,g4,r)];
        f16x8 hh1 = *(const f16x8*)&H0B[HBI(pH0r,0,1,g4,r)];
        f16x8 hl1 = *(const f16x8*)&H0B[HBI(pH0r,1,1,g4,r)];
        #pragma unroll
        for (int mt = 0; mt < 2; ++mt) {
            f32x4 z = {0.0f, 0.0f, 0.0f, 0.0f};
            z = MFMA(wa[0][mt], xh,  z);
            z = MFMA(wa[0][mt], xl,  z);
            z = MFMA(wa[1][mt], hh0, z);
            z = MFMA(wa[1][mt], hl0, z);
            z = MFMA(wa[2][mt], hh1, z);
            z = MFMA(wa[2][mt], hl1, z);
            const int u = (m0 + mt) * 4 + g4;
            float ig = sig2(z[0]), fg = sig2(z[1]);
            float gg = tanh2(z[2]), og = sig2(z[3]);
            float c = fmaf(fg, c0[mt][nt], ig * gg);
            c0[mt][nt] = c;
            float h = og * tanhc(c);
            f16 hh = (f16)h, hl = (f16)(h - (float)hh);
            H0B[HBI(pH0w,0,(u>>5),(u>>3)&3,r) + (u&7)] = hh;
            H0B[HBI(pH0w,1,(u>>5),(u>>3)&3,r) + (u&7)] = hl;
        }
    }
}

// ---- standalone layer 1 (epilogue + decoder)
template<bool DEC>
__device__ __forceinline__ void layer1_only(
    int pH0, int pH1r, int pH1w, int m0, int lane,
    const f16x8 (&wa)[7][2], const f32x4 (&b1)[2], float (&c1)[2][4],
    const f16* __restrict__ H0B, f16* __restrict__ H1B, float* __restrict__ H1F)
{
    const int g4 = lane >> 4, l15 = lane & 15;
    #pragma unroll
    for (int nt = 0; nt < 4; ++nt) {
        const int r = nt * 16 + l15;
        f16x8 hh0 = *(const f16x8*)&H0B[HBI(pH0,0,0,g4,r)];
        f16x8 hl0 = *(const f16x8*)&H0B[HBI(pH0,1,0,g4,r)];
        f16x8 hh1 = *(const f16x8*)&H0B[HBI(pH0,0,1,g4,r)];
        f16x8 hl1 = *(const f16x8*)&H0B[HBI(pH0,1,1,g4,r)];
        f16x8 gh0 = *(const f16x8*)&H1B[HBI(pH1r,0,0,g4,r)];
        f16x8 gl0 = *(const f16x8*)&H1B[HBI(pH1r,1,0,g4,r)];
        f16x8 gh1 = *(const f16x8*)&H1B[HBI(pH1r,0,1,g4,r)];
        f16x8 gl1 = *(const f16x8*)&H1B[HBI(pH1r,1,1,g4,r)];
        #pragma unroll
        for (int mt = 0; mt < 2; ++mt) {
            f32x4 a = b1[mt];
            a = MFMA(wa[3][mt], hh0, a);
            a = MFMA(wa[3][mt], hl0, a);
            a = MFMA(wa[4][mt], hh1, a);
            a = MFMA(wa[4][mt], hl1, a);
            a = MFMA(wa[5][mt], gh0, a);
            a = MFMA(wa[5][mt], gl0, a);
            a = MFMA(wa[6][mt], gh1, a);
            a = MFMA(wa[6][mt], gl1, a);
            const int u = (m0 + mt) * 4 + g4;
            float ig = sig2(a[0]), fg = sig2(a[1]);
            float gg = tanh2(a[2]), og = sig2(a[3]);
            float c = fmaf(fg, c1[mt][nt], ig * gg);
            c1[mt][nt] = c;
            float h = og * tanhc(c);
            f16 hh = (f16)h, hl = (f16)(h - (float)hh);
            H1B[HBI(pH1w,0,(u>>5),(u>>3)&3,r) + (u&7)] = hh;
            H1B[HBI(pH1w,1,(u>>5),(u>>3)&3,r) + (u&7)] = hl;
            if (DEC) H1F[u * 64 + r] = h;
        }
    }
}

// ---- fused encoder phase t: {L1_t ; L0_{t+1}} — ONE barrier per timestep.
// p = t&1. h0_t in H0B[p]; h1_{t-1} in H1B[p^1]; x_{t+1} in XB[p^1].
// Writes h1_t -> H1B[p], h0_{t+1} -> H0B[p^1]. L1 and L0 SHARE the h0_t frags.
__device__ __forceinline__ void enc_phase(
    int p, int m0, int lane,
    const f16x8 (&wa)[7][2], const f32x4 (&b1)[2],
    float (&c0)[2][4], float (&c1)[2][4],
    const f16* __restrict__ XB, f16* __restrict__ H0B, f16* __restrict__ H1B)
{
    const int g4 = lane >> 4, l15 = lane & 15;
    const int q = p ^ 1;
    #pragma unroll
    for (int nt = 0; nt < 4; ++nt) {
        const int r = nt * 16 + l15;
        f16x8 hh0 = *(const f16x8*)&H0B[HBI(p,0,0,g4,r)];   // h0_t (shared L1/L0)
        f16x8 hl0 = *(const f16x8*)&H0B[HBI(p,1,0,g4,r)];
        f16x8 hh1 = *(const f16x8*)&H0B[HBI(p,0,1,g4,r)];
        f16x8 hl1 = *(const f16x8*)&H0B[HBI(p,1,1,g4,r)];
        f16x8 gh0 = *(const f16x8*)&H1B[HBI(q,0,0,g4,r)];   // h1_{t-1}
        f16x8 gl0 = *(const f16x8*)&H1B[HBI(q,1,0,g4,r)];
        f16x8 gh1 = *(const f16x8*)&H1B[HBI(q,0,1,g4,r)];
        f16x8 gl1 = *(const f16x8*)&H1B[HBI(q,1,1,g4,r)];
        // ---- L1_t (both mt) ----
        #pragma unroll
        for (int mt = 0; mt < 2; ++mt) {
            const int u = (m0 + mt) * 4 + g4;
            f32x4 a = b1[mt];
            a = MFMA(wa[3][mt], hh0, a);
            a = MFMA(wa[3][mt], hl0, a);
            a = MFMA(wa[4][mt], hh1, a);
            a = MFMA(wa[4][mt], hl1, a);
            a = MFMA(wa[5][mt], gh0, a);
            a = MFMA(wa[5][mt], gl0, a);
            a = MFMA(wa[6][mt], gh1, a);
            a = MFMA(wa[6][mt], gl1, a);
            float ig = sig2(a[0]), fg = sig2(a[1]);
            float gg = tanh2(a[2]), og = sig2(a[3]);
            float c = fmaf(fg, c1[mt][nt], ig * gg);
            c1[mt][nt] = c;
            float h = og * tanhc(c);
            f16 hh = (f16)h, hl = (f16)(h - (float)hh);
            H1B[HBI(p,0,(u>>5),(u>>3)&3,r) + (u&7)] = hh;
            H1B[HBI(p,1,(u>>5),(u>>3)&3,r) + (u&7)] = hl;
        }
        // ---- L0_{t+1} (both mt) ----
        f16x8 xh = *(const f16x8*)&XB[XBI(q,0,g4,r)];       // x_{t+1}
        f16x8 xl = *(const f16x8*)&XB[XBI(q,1,g4,r)];
        #pragma unroll
        for (int mt = 0; mt < 2; ++mt) {
            const int u = (m0 + mt) * 4 + g4;
            f32x4 z = {0.0f, 0.0f, 0.0f, 0.0f};
            z = MFMA(wa[0][mt], xh,  z);
            z = MFMA(wa[0][mt], xl,  z);
            z = MFMA(wa[1][mt], hh0, z);
            z = MFMA(wa[1][mt], hl0, z);
            z = MFMA(wa[2][mt], hh1, z);
            z = MFMA(wa[2][mt], hl1, z);
            float ig = sig2(z[0]), fg = sig2(z[1]);
            float gg = tanh2(z[2]), og = sig2(z[3]);
            float c = fmaf(fg, c0[mt][nt], ig * gg);
            c0[mt][nt] = c;
            float h = og * tanhc(c);
            f16 hh = (f16)h, hl = (f16)(h - (float)hh);
            H0B[HBI(q,0,(u>>5),(u>>3)&3,r) + (u&7)] = hh;
            H0B[HBI(q,1,(u>>5),(u>>3)&3,r) + (u&7)] = hl;
        }
    }
}

// 512 threads = 8 waves; wave w owns M-tiles {2w,2w+1} (units 8w..8w+7);
// 64 batch rows per block; grid = 256 (1 block/CU, LDS-capped). Weights persist
// in VGPRs: 2-term scheme (W f16 single plane = 56 VGPR), h staged hi/lo.
// No waves_per_eu attribute: R4 showed forcing 64 VGPR causes catastrophic spill;
// default allocation (128) now FITS the ~130-reg live set.
__global__ __launch_bounds__(512) void lstm_kernel(
    const float* __restrict__ src, const float* __restrict__ ws,
    float* __restrict__ out)
{
    __shared__ __align__(16) f16 XB [2*2*4*64*8];     // 16 KB
    __shared__ __align__(16) f16 H0B[2*2*2*4*64*8];   // 32 KB
    __shared__ __align__(16) f16 H1B[2*2*2*4*64*8];   // 32 KB
    __shared__ float H1F[64*64];                      // 16 KB (decoder fc)
    __shared__ float FCW[64];

    const int tid  = threadIdx.x;
    const int lane = tid & 63;
    const int wave = __builtin_amdgcn_readfirstlane(tid >> 6);
    const int m0   = wave * 2;
    const int g4   = lane >> 4;
    const int rowBase = blockIdx.x * 64;

    float c0[2][4], c1[2][4];
    #pragma unroll
    for (int mt = 0; mt < 2; ++mt)
        #pragma unroll
        for (int nt = 0; nt < 4; ++nt) { c0[mt][nt] = 0.0f; c1[mt][nt] = 0.0f; }

    f16x8 wa[7][2];             // [kt: 0-2 L0, 3-6 L1][mt], hi plane only
    f32x4 b1[2];

    auto ldw = [&](int off0, int off1, int ob1) {
        #pragma unroll
        for (int kt = 0; kt < 3; ++kt)
            #pragma unroll
            for (int mt = 0; mt < 2; ++mt)
                wa[kt][mt] = *(const f16x8*)(ws + off0 +
                    ((((m0 + mt) * 3 + kt) * 64 + lane) * 2) * 4);
        #pragma unroll
        for (int kt = 0; kt < 4; ++kt)
            #pragma unroll
            for (int mt = 0; mt < 2; ++mt)
                wa[3 + kt][mt] = *(const f16x8*)(ws + off1 +
                    ((((m0 + mt) * 4 + kt) * 64 + lane) * 2) * 4);
        #pragma unroll
        for (int mt = 0; mt < 2; ++mt)
            b1[mt] = *(const f32x4*)(ws + ob1 + (m0 + mt) * 16 + g4 * 4);
    };
    ldw(OFF_E0, OFF_E1, OFF_BE1);

    // zero XB (fully) and parity-1 halves of H0B/H1B (h0_{-1} = h1_{-1} = 0)
    for (int i = tid; i < 2*2*4*64*8; i += 512) XB[i] = (f16)0;
    for (int i = tid; i < 8192; i += 512) { H0B[8192 + i] = (f16)0; H1B[8192 + i] = (f16)0; }
    if (tid < 64) FCW[tid] = ws[OFF_FCW + tid];
    const float fcbv = ws[OFF_FCB];

    const float* sp = src + (size_t)(rowBase + lane) * (S_ * IN_);
    __syncthreads();

    // stage x0 -> XB[0], x1 -> XB[1]
    if (wave == 7) {
        float xv[IN_];
        #pragma unroll
        for (int i = 0; i < IN_; ++i) xv[i] = sp[i];
        stage_x5(XB, 0, lane, xv);
        #pragma unroll
        for (int i = 0; i < IN_; ++i) xv[i] = sp[IN_ + i];
        stage_x5(XB, 1, lane, xv);
    }
    __syncthreads();

    // prologue: L0_0 (reads XB[0], H0B[1](=0), writes H0B[0])
    layer0_only(0, 1, 0, m0, lane, wa, c0, XB, H0B);
    __syncthreads();

    // ---------------- encoder: fused phases, ONE barrier per timestep ----------
    #pragma unroll 1
    for (int t = 0; t < S_ - 1; ++t) {
        const int p = t & 1;
        float xv[IN_];
        const bool pf = (wave == 7) && (t + 2 < S_);
        if (pf) {
            #pragma unroll
            for (int i = 0; i < IN_; ++i) xv[i] = sp[(t + 2) * IN_ + i];
        }
        enc_phase(p, m0, lane, wa, b1, c0, c1, XB, H0B, H1B);
        if (pf) stage_x5(XB, p, lane, xv);   // x_{t+2} -> XB[(t+2)&1] = XB[p]
        __syncthreads();
    }

    // epilogue: L1_{S-1} (reads H0B[1], H1B[0], writes H1B[1])
    layer1_only<false>(1, 0, 1, m0, lane, wa, b1, c1, H0B, H1B, H1F);
    __syncthreads();

    // ---------------- decoder ----------------
    ldw(OFF_D0, OFF_D1, OFF_BD1);
    if (wave == 7) stage_x1(XB, 0, lane, sp[(S_ - 1) * IN_ + 3]);   // dec_in0
    __syncthreads();

    #pragma unroll 1
    for (int t = 0; t < T_; ++t) {
        const int q = t & 1;
        layer0_only(q, q ^ 1, q, m0, lane, wa, c0, XB, H0B);
        __syncthreads();
        layer1_only<true>(q, q ^ 1, q, m0, lane, wa, b1, c1, H0B, H1B, H1F);
        __syncthreads();
        if (wave == 0) {   // fc head: pred = fcW . h1_new + fcb  (lane = row)
            float pv = fcbv;
            #pragma unroll 4
            for (int k = 0; k < 64; ++k) pv = fmaf(FCW[k], H1F[k * 64 + lane], pv);
            out[(size_t)(rowBase + lane) * T_ + t] = pv;
            if (t + 1 < T_) stage_x1(XB, q ^ 1, lane, pv);
        }
        __syncthreads();
    }
}

extern "C" void kernel_launch(void* const* d_in, const int* in_sizes, int n_in,
                              void* d_out, int out_size, void* d_ws, size_t ws_size,
                              hipStream_t stream)
{
    const float* src = (const float*)d_in[0];
    float* ws  = (float*)d_ws;
    float* out = (float*)d_out;

    prep_kernel<<<(WS_TOT + 255) / 256, 256, 0, stream>>>(
        (const float*)d_in[1],  (const float*)d_in[2],
        (const float*)d_in[3],  (const float*)d_in[4],
        (const float*)d_in[5],  (const float*)d_in[6],
        (const float*)d_in[7],  (const float*)d_in[8],
        (const float*)d_in[9],  (const float*)d_in[10],
        (const float*)d_in[11], (const float*)d_in[12],
        (const float*)d_in[13], (const float*)d_in[14],
        (const float*)d_in[15], (const float*)d_in[16],
        (const float*)d_in[17], (const float*)d_in[18],
        ws);

    lstm_kernel<<<B_ / 64, 512, 0, stream>>>(src, ws, out);
}

// Round 6
// 1744.696 us; speedup vs baseline: 2.1813x; 1.0006x over previous
//
#include <hip/hip_runtime.h>
#include <stdint.h>

#define B_ 16384
#define S_ 336
#define T_ 48
#define IN_ 5
#define H_ 64

#define ROWS 32              // batch rows per block
#define NT   (ROWS / 16)     // N-tiles per wave
#define GP   (ROWS * 8)      // f16 stride per g-group

typedef _Float16 f16;
typedef _Float16 f16x8 __attribute__((ext_vector_type(8)));
typedef float f32x4 __attribute__((ext_vector_type(4)));

#define LOG2E 1.44269504088896340736f

// ---- ws layout (float words) ----
// A-fragment packed weights: [mt16][kt][lane64][pl2][reg4] u32 words (pl=1 unused)
// Weights & biases PRE-SCALED: gate rows i,f,o by -log2e, gate g by +2*log2e.
// L0 x-chunk slot k==5 carries the L0 bias (bih+bhh); B-side stages 1.0 there.
#define OFF_E0 0
#define OFF_E1 24576
#define OFF_D0 57344
#define OFF_D1 81920
#define OFF_BE0 114688
#define OFF_BE1 114944
#define OFF_BD0 115200
#define OFF_BD1 115456
#define OFF_FCW 115712
#define OFF_FCB 115776
#define WS_TOT  115777

__device__ __forceinline__ float sig2(float g) {     // sigmoid(z), g = -log2e*z
    return __builtin_amdgcn_rcpf(1.0f + __builtin_amdgcn_exp2f(g));
}
__device__ __forceinline__ float tanh2(float g) {    // tanh(z), g = 2*log2e*z
    return 1.0f - 2.0f * __builtin_amdgcn_rcpf(1.0f + __builtin_amdgcn_exp2f(g));
}
__device__ __forceinline__ float tanhc(float c) {    // tanh(c), raw c
    return 1.0f - 2.0f * __builtin_amdgcn_rcpf(1.0f + __builtin_amdgcn_exp2f(c * (2.0f * LOG2E)));
}

// ---------------- prep: pack weights into MFMA A-fragment layout ----
__global__ void prep_kernel(
    const float* __restrict__ eWih0, const float* __restrict__ eWhh0,
    const float* __restrict__ ebih0, const float* __restrict__ ebhh0,
    const float* __restrict__ eWih1, const float* __restrict__ eWhh1,
    const float* __restrict__ ebih1, const float* __restrict__ ebhh1,
    const float* __restrict__ dWih0, const float* __restrict__ dWhh0,
    const float* __restrict__ dbih0, const float* __restrict__ dbhh0,
    const float* __restrict__ dWih1, const float* __restrict__ dWhh1,
    const float* __restrict__ dbih1, const float* __restrict__ dbhh1,
    const float* __restrict__ fcW,  const float* __restrict__ fcb,
    float* __restrict__ ws)
{
    int idx = blockIdx.x * blockDim.x + threadIdx.x;
    if (idx >= WS_TOT) return;
    float outv;
    if (idx < OFF_BE0) {
        int rel, nkt, xdim;
        const float *Wi, *Wh, *bi, *bh;
        if (idx < OFF_E1)      { rel = idx - OFF_E0; nkt = 3; xdim = IN_; Wi = eWih0; Wh = eWhh0; bi = ebih0; bh = ebhh0; }
        else if (idx < OFF_D0) { rel = idx - OFF_E1; nkt = 4; xdim = 64;  Wi = eWih1; Wh = eWhh1; bi = 0; bh = 0; }
        else if (idx < OFF_D1) { rel = idx - OFF_D0; nkt = 3; xdim = 1;   Wi = dWih0; Wh = dWhh0; bi = dbih0; bh = dbhh0; }
        else                   { rel = idx - OFF_D1; nkt = 4; xdim = 64;  Wi = dWih1; Wh = dWhh1; bi = 0; bh = 0; }
        int reg = rel & 3, pl = (rel >> 2) & 1, lane = (rel >> 3) & 63;
        int rest = rel >> 9;
        int kt = rest % nkt, mt = rest / nkt;
        int gp = mt * 16 + (lane & 15);
        int type = gp & 3;
        int j  = type * 64 + (gp >> 2);
        float sc = (type == 2) ? (2.0f * LOG2E) : (-LOG2E);
        union { f16 h2[2]; float f; } u_;
        #pragma unroll
        for (int h = 0; h < 2; ++h) {
            int k = kt * 32 + (lane >> 4) * 8 + reg * 2 + h;
            float v;
            if (nkt == 4)      v = (k < 64) ? Wi[j * 64 + k] : Wh[j * 64 + (k - 64)];
            else if (k < xdim) v = Wi[j * xdim + k];
            else if (k == 5)   v = bi[j] + bh[j];      // L0 bias in slot 5
            else if (k >= 32)  v = Wh[j * 64 + (k - 32)];
            else               v = 0.0f;
            v *= sc;
            f16 hi = (f16)v;
            u_.h2[h] = (pl == 0) ? hi : (f16)(v - (float)hi);
        }
        outv = u_.f;
    } else if (idx < OFF_FCW) {
        int rel = idx - OFF_BE0;
        int which = rel >> 8, gp = rel & 255;
        int type = gp & 3;
        int j = type * 64 + (gp >> 2);
        float sc = (type == 2) ? (2.0f * LOG2E) : (-LOG2E);
        const float *bi, *bh;
        if (which == 0)      { bi = ebih0; bh = ebhh0; }
        else if (which == 1) { bi = ebih1; bh = ebhh1; }
        else if (which == 2) { bi = dbih0; bh = dbhh0; }
        else                 { bi = dbih1; bh = dbhh1; }
        outv = (bi[j] + bh[j]) * sc;
    } else if (idx < OFF_FCB) {
        outv = fcW[idx - OFF_FCW];
    } else {
        outv = fcb[0];
    }
    ws[idx] = outv;
}

// LDS index helpers (f16 element index), ROWS=32 geometry
#define XBI(b,p,g,r)   ((((b)*2+(p))*4+(g))*GP + (r)*8)
#define HBI(b,p,k,g,r) (((((b)*2+(p))*2+(k))*4+(g))*GP + (r)*8)
#define XTOT (2*2*4*GP)      // 4096 f16
#define HHALF (2*2*4*GP)     // one buf of H0B/H1B: 4096 f16

#define MFMA(a,b,c) __builtin_amdgcn_mfma_f32_16x16x32_f16(a, b, c, 0, 0, 0)

__device__ __forceinline__ void stage_x5(f16* __restrict__ XB, int b, int r, const float* xv) {
    f16x8 ph, pl_;
    #pragma unroll
    for (int i = 0; i < 8; ++i) { ph[i] = (f16)0; pl_[i] = (f16)0; }
    #pragma unroll
    for (int i = 0; i < IN_; ++i) {
        f16 hh = (f16)xv[i]; ph[i] = hh; pl_[i] = (f16)(xv[i] - (float)hh);
    }
    ph[5] = (f16)1.0f;          // bias slot
    *(f16x8*)&XB[XBI(b,0,0,r)] = ph;
    *(f16x8*)&XB[XBI(b,1,0,r)] = pl_;
}
__device__ __forceinline__ void stage_x1(f16* __restrict__ XB, int b, int r, float v) {
    f16x8 ph, pl_;
    #pragma unroll
    for (int i = 0; i < 8; ++i) { ph[i] = (f16)0; pl_[i] = (f16)0; }
    f16 hh = (f16)v; ph[0] = hh; pl_[0] = (f16)(v - (float)hh);
    ph[5] = (f16)1.0f;          // bias slot
    *(f16x8*)&XB[XBI(b,0,0,r)] = ph;
    *(f16x8*)&XB[XBI(b,1,0,r)] = pl_;
}

// ---- standalone layer 0 (prologue + decoder): acc starts at 0 (bias in slot 5)
__device__ __forceinline__ void layer0_only(
    int pX, int pH0r, int pH0w, int m0, int lane,
    const f16x8 (&wa)[7][2], float (&c0)[2][NT],
    const f16* __restrict__ XB, f16* __restrict__ H0B)
{
    const int g4 = lane >> 4, l15 = lane & 15;
    #pragma unroll
    for (int nt = 0; nt < NT; ++nt) {
        const int r = nt * 16 + l15;
        f16x8 xh  = *(const f16x8*)&XB [XBI(pX,0,g4,r)];
        f16x8 xl  = *(const f16x8*)&XB [XBI(pX,1,g4,r)];
        f16x8 hh0 = *(const f16x8*)&H0B[HBI(pH0r,0,0,g4,r)];
        f16x8 hl0 = *(const f16x8*)&H0B[HBI(pH0r,1,0,g4,r)];
        f16x8 hh1 = *(const f16x8*)&H0B[HBI(pH0r,0,1,g4,r)];
        f16x8 hl1 = *(const f16x8*)&H0B[HBI(pH0r,1,1,g4,r)];
        #pragma unroll
        for (int mt = 0; mt < 2; ++mt) {
            f32x4 z = {0.0f, 0.0f, 0.0f, 0.0f};
            z = MFMA(wa[0][mt], xh,  z);
            z = MFMA(wa[0][mt], xl,  z);
            z = MFMA(wa[1][mt], hh0, z);
            z = MFMA(wa[1][mt], hl0, z);
            z = MFMA(wa[2][mt], hh1, z);
            z = MFMA(wa[2][mt], hl1, z);
            const int u = (m0 + mt) * 4 + g4;
            float ig = sig2(z[0]), fg = sig2(z[1]);
            float gg = tanh2(z[2]), og = sig2(z[3]);
            float c = fmaf(fg, c0[mt][nt], ig * gg);
            c0[mt][nt] = c;
            float h = og * tanhc(c);
            f16 hh = (f16)h, hl = (f16)(h - (float)hh);
            H0B[HBI(pH0w,0,(u>>5),(u>>3)&3,r) + (u&7)] = hh;
            H0B[HBI(pH0w,1,(u>>5),(u>>3)&3,r) + (u&7)] = hl;
        }
    }
}

// ---- standalone layer 1 (epilogue + decoder)
template<bool DEC>
__device__ __forceinline__ void layer1_only(
    int pH0, int pH1r, int pH1w, int m0, int lane,
    const f16x8 (&wa)[7][2], const f32x4 (&b1)[2], float (&c1)[2][NT],
    const f16* __restrict__ H0B, f16* __restrict__ H1B, float* __restrict__ H1F)
{
    const int g4 = lane >> 4, l15 = lane & 15;
    #pragma unroll
    for (int nt = 0; nt < NT; ++nt) {
        const int r = nt * 16 + l15;
        f16x8 hh0 = *(const f16x8*)&H0B[HBI(pH0,0,0,g4,r)];
        f16x8 hl0 = *(const f16x8*)&H0B[HBI(pH0,1,0,g4,r)];
        f16x8 hh1 = *(const f16x8*)&H0B[HBI(pH0,0,1,g4,r)];
        f16x8 hl1 = *(const f16x8*)&H0B[HBI(pH0,1,1,g4,r)];
        f16x8 gh0 = *(const f16x8*)&H1B[HBI(pH1r,0,0,g4,r)];
        f16x8 gl0 = *(const f16x8*)&H1B[HBI(pH1r,1,0,g4,r)];
        f16x8 gh1 = *(const f16x8*)&H1B[HBI(pH1r,0,1,g4,r)];
        f16x8 gl1 = *(const f16x8*)&H1B[HBI(pH1r,1,1,g4,r)];
        #pragma unroll
        for (int mt = 0; mt < 2; ++mt) {
            f32x4 a = b1[mt];
            a = MFMA(wa[3][mt], hh0, a);
            a = MFMA(wa[3][mt], hl0, a);
            a = MFMA(wa[4][mt], hh1, a);
            a = MFMA(wa[4][mt], hl1, a);
            a = MFMA(wa[5][mt], gh0, a);
            a = MFMA(wa[5][mt], gl0, a);
            a = MFMA(wa[6][mt], gh1, a);
            a = MFMA(wa[6][mt], gl1, a);
            const int u = (m0 + mt) * 4 + g4;
            float ig = sig2(a[0]), fg = sig2(a[1]);
            float gg = tanh2(a[2]), og = sig2(a[3]);
            float c = fmaf(fg, c1[mt][nt], ig * gg);
            c1[mt][nt] = c;
            float h = og * tanhc(c);
            f16 hh = (f16)h, hl = (f16)(h - (float)hh);
            H1B[HBI(pH1w,0,(u>>5),(u>>3)&3,r) + (u&7)] = hh;
            H1B[HBI(pH1w,1,(u>>5),(u>>3)&3,r) + (u&7)] = hl;
            if (DEC) H1F[u * 33 + r] = h;
        }
    }
}

// ---- fused encoder phase t: {L1_t ; L0_{t+1}} — ONE barrier per timestep.
// p = t&1. h0_t in H0B[p]; h1_{t-1} in H1B[p^1]; x_{t+1} in XB[p^1].
// Writes h1_t -> H1B[p], h0_{t+1} -> H0B[p^1]. L1 and L0 SHARE the h0_t frags.
__device__ __forceinline__ void enc_phase(
    int p, int m0, int lane,
    const f16x8 (&wa)[7][2], const f32x4 (&b1)[2],
    float (&c0)[2][NT], float (&c1)[2][NT],
    const f16* __restrict__ XB, f16* __restrict__ H0B, f16* __restrict__ H1B)
{
    const int g4 = lane >> 4, l15 = lane & 15;
    const int q = p ^ 1;
    #pragma unroll
    for (int nt = 0; nt < NT; ++nt) {
        const int r = nt * 16 + l15;
        f16x8 hh0 = *(const f16x8*)&H0B[HBI(p,0,0,g4,r)];   // h0_t (shared L1/L0)
        f16x8 hl0 = *(const f16x8*)&H0B[HBI(p,1,0,g4,r)];
        f16x8 hh1 = *(const f16x8*)&H0B[HBI(p,0,1,g4,r)];
        f16x8 hl1 = *(const f16x8*)&H0B[HBI(p,1,1,g4,r)];
        f16x8 gh0 = *(const f16x8*)&H1B[HBI(q,0,0,g4,r)];   // h1_{t-1}
        f16x8 gl0 = *(const f16x8*)&H1B[HBI(q,1,0,g4,r)];
        f16x8 gh1 = *(const f16x8*)&H1B[HBI(q,0,1,g4,r)];
        f16x8 gl1 = *(const f16x8*)&H1B[HBI(q,1,1,g4,r)];
        // ---- L1_t (both mt) ----
        #pragma unroll
        for (int mt = 0; mt < 2; ++mt) {
            const int u = (m0 + mt) * 4 + g4;
            f32x4 a = b1[mt];
            a = MFMA(wa[3][mt], hh0, a);
            a = MFMA(wa[3][mt], hl0, a);
            a = MFMA(wa[4][mt], hh1, a);
            a = MFMA(wa[4][mt], hl1, a);
            a = MFMA(wa[5][mt], gh0, a);
            a = MFMA(wa[5][mt], gl0, a);
            a = MFMA(wa[6][mt], gh1, a);
            a = MFMA(wa[6][mt], gl1, a);
            float ig = sig2(a[0]), fg = sig2(a[1]);
            float gg = tanh2(a[2]), og = sig2(a[3]);
            float c = fmaf(fg, c1[mt][nt], ig * gg);
            c1[mt][nt] = c;
            float h = og * tanhc(c);
            f16 hh = (f16)h, hl = (f16)(h - (float)hh);
            H1B[HBI(p,0,(u>>5),(u>>3)&3,r) + (u&7)] = hh;
            H1B[HBI(p,1,(u>>5),(u>>3)&3,r) + (u&7)] = hl;
        }
        // ---- L0_{t+1} (both mt) ----
        f16x8 xh = *(const f16x8*)&XB[XBI(q,0,g4,r)];       // x_{t+1}
        f16x8 xl = *(const f16x8*)&XB[XBI(q,1,g4,r)];
        #pragma unroll
        for (int mt = 0; mt < 2; ++mt) {
            const int u = (m0 + mt) * 4 + g4;
            f32x4 z = {0.0f, 0.0f, 0.0f, 0.0f};
            z = MFMA(wa[0][mt], xh,  z);
            z = MFMA(wa[0][mt], xl,  z);
            z = MFMA(wa[1][mt], hh0, z);
            z = MFMA(wa[1][mt], hl0, z);
            z = MFMA(wa[2][mt], hh1, z);
            z = MFMA(wa[2][mt], hl1, z);
            float ig = sig2(z[0]), fg = sig2(z[1]);
            float gg = tanh2(z[2]), og = sig2(z[3]);
            float c = fmaf(fg, c0[mt][nt], ig * gg);
            c0[mt][nt] = c;
            float h = og * tanhc(c);
            f16 hh = (f16)h, hl = (f16)(h - (float)hh);
            H0B[HBI(q,0,(u>>5),(u>>3)&3,r) + (u&7)] = hh;
            H0B[HBI(q,1,(u>>5),(u>>3)&3,r) + (u&7)] = hl;
        }
    }
}

// 512 threads = 8 waves; wave w owns M-tiles {2w,2w+1} (units 8w..8w+7);
// ROWS=32 batch rows/block; grid = 512 -> 2 blocks/CU. Independent blocks drift
// anti-phase so one block's activation VALU overlaps the other's MFMA.
// NO occupancy attribute: R4 proved forcing 64 VGPR = catastrophic spill;
// R5 measured the live set at 108 regs, which fits the 128/4-wave budget as-is.
// LDS ~49 KB (<80 KB) so LDS no longer caps at 1 block/CU.
__global__ __launch_bounds__(512) void lstm_kernel(
    const float* __restrict__ src, const float* __restrict__ ws,
    float* __restrict__ out)
{
    __shared__ __align__(16) f16 XB [XTOT];           // 8 KB
    __shared__ __align__(16) f16 H0B[2*HHALF];        // 16 KB
    __shared__ __align__(16) f16 H1B[2*HHALF];        // 16 KB
    __shared__ float H1F[64*33];                      // 8.25 KB (decoder fc)
    __shared__ float FCW[64];

    const int tid  = threadIdx.x;
    const int lane = tid & 63;
    const int wave = __builtin_amdgcn_readfirstlane(tid >> 6);
    const int m0   = wave * 2;
    const int g4   = lane >> 4;
    const int rowBase = blockIdx.x * ROWS;

    float c0[2][NT], c1[2][NT];
    #pragma unroll
    for (int mt = 0; mt < 2; ++mt)
        #pragma unroll
        for (int nt = 0; nt < NT; ++nt) { c0[mt][nt] = 0.0f; c1[mt][nt] = 0.0f; }

    f16x8 wa[7][2];             // [kt: 0-2 L0, 3-6 L1][mt], hi plane only
    f32x4 b1[2];

    auto ldw = [&](int off0, int off1, int ob1) {
        #pragma unroll
        for (int kt = 0; kt < 3; ++kt)
            #pragma unroll
            for (int mt = 0; mt < 2; ++mt)
                wa[kt][mt] = *(const f16x8*)(ws + off0 +
                    ((((m0 + mt) * 3 + kt) * 64 + lane) * 2) * 4);
        #pragma unroll
        for (int kt = 0; kt < 4; ++kt)
            #pragma unroll
            for (int mt = 0; mt < 2; ++mt)
                wa[3 + kt][mt] = *(const f16x8*)(ws + off1 +
                    ((((m0 + mt) * 4 + kt) * 64 + lane) * 2) * 4);
        #pragma unroll
        for (int mt = 0; mt < 2; ++mt)
            b1[mt] = *(const f32x4*)(ws + ob1 + (m0 + mt) * 16 + g4 * 4);
    };
    ldw(OFF_E0, OFF_E1, OFF_BE1);

    // zero XB (fully) and parity-1 halves of H0B/H1B (h0_{-1} = h1_{-1} = 0)
    for (int i = tid; i < XTOT; i += 512) XB[i] = (f16)0;
    for (int i = tid; i < HHALF; i += 512) { H0B[HHALF + i] = (f16)0; H1B[HHALF + i] = (f16)0; }
    if (tid < 64) FCW[tid] = ws[OFF_FCW + tid];
    const float fcbv = ws[OFF_FCB];

    const int xr = lane & (ROWS - 1);
    const float* sp = src + (size_t)(rowBase + xr) * (S_ * IN_);
    __syncthreads();

    // stage x0 -> XB[0], x1 -> XB[1]
    if (wave == 7 && lane < ROWS) {
        float xv[IN_];
        #pragma unroll
        for (int i = 0; i < IN_; ++i) xv[i] = sp[i];
        stage_x5(XB, 0, lane, xv);
        #pragma unroll
        for (int i = 0; i < IN_; ++i) xv[i] = sp[IN_ + i];
        stage_x5(XB, 1, lane, xv);
    }
    __syncthreads();

    // prologue: L0_0 (reads XB[0], H0B[1](=0), writes H0B[0])
    layer0_only(0, 1, 0, m0, lane, wa, c0, XB, H0B);
    __syncthreads();

    // ---------------- encoder: fused phases, ONE barrier per timestep ----------
    #pragma unroll 1
    for (int t = 0; t < S_ - 1; ++t) {
        const int p = t & 1;
        float xv[IN_];
        const bool pf = (wave == 7) && (lane < ROWS) && (t + 2 < S_);
        if (pf) {
            #pragma unroll
            for (int i = 0; i < IN_; ++i) xv[i] = sp[(t + 2) * IN_ + i];
        }
        enc_phase(p, m0, lane, wa, b1, c0, c1, XB, H0B, H1B);
        if (pf) stage_x5(XB, p, lane, xv);   // x_{t+2} -> XB[(t+2)&1] = XB[p]
        __syncthreads();
    }

    // epilogue: L1_{S-1} (reads H0B[1], H1B[0], writes H1B[1])
    layer1_only<false>(1, 0, 1, m0, lane, wa, b1, c1, H0B, H1B, H1F);
    __syncthreads();

    // ---------------- decoder ----------------
    ldw(OFF_D0, OFF_D1, OFF_BD1);
    if (wave == 7 && lane < ROWS) stage_x1(XB, 0, lane, sp[(S_ - 1) * IN_ + 3]);
    __syncthreads();

    #pragma unroll 1
    for (int t = 0; t < T_; ++t) {
        const int q = t & 1;
        layer0_only(q, q ^ 1, q, m0, lane, wa, c0, XB, H0B);
        __syncthreads();
        layer1_only<true>(q, q ^ 1, q, m0, lane, wa, b1, c1, H0B, H1B, H1F);
        __syncthreads();
        if (wave == 0 && lane < ROWS) {   // fc head (lane = row)
            float pv = fcbv;
            #pragma unroll 4
            for (int k = 0; k < 64; ++k) pv = fmaf(FCW[k], H1F[k * 33 + lane], pv);
            out[(size_t)(rowBase + lane) * T_ + t] = pv;
            if (t + 1 < T_) stage_x1(XB, q ^ 1, lane, pv);
        }
        __syncthreads();
    }
}

extern "C" void kernel_launch(void* const* d_in, const int* in_sizes, int n_in,
                              void* d_out, int out_size, void* d_ws, size_t ws_size,
                              hipStream_t stream)
{
    const float* src = (const float*)d_in[0];
    float* ws  = (float*)d_ws;
    float* out = (float*)d_out;

    prep_kernel<<<(WS_TOT + 255) / 256, 256, 0, stream>>>(
        (const float*)d_in[1],  (const float*)d_in[2],
        (const float*)d_in[3],  (const float*)d_in[4],
        (const float*)d_in[5],  (const float*)d_in[6],
        (const float*)d_in[7],  (const float*)d_in[8],
        (const float*)d_in[9],  (const float*)d_in[10],
        (const float*)d_in[11], (const float*)d_in[12],
        (const float*)d_in[13], (const float*)d_in[14],
        (const float*)d_in[15], (const float*)d_in[16],
        (const float*)d_in[17], (const float*)d_in[18],
        ws);

    lstm_kernel<<<B_ / ROWS, 512, 0, stream>>>(src, ws, out);
}

// Round 7
// 1685.091 us; speedup vs baseline: 2.2585x; 1.0354x over previous
//
#include <hip/hip_runtime.h>
#include <stdint.h>

#define B_ 16384
#define S_ 336
#define T_ 48
#define IN_ 5
#define H_ 64

#define ROWS 32              // batch rows per block
#define NT   (ROWS / 16)     // N-tiles per wave
#define GP   (ROWS * 8)      // f16 stride per g-group

typedef _Float16 f16;
typedef _Float16 f16x8 __attribute__((ext_vector_type(8)));
typedef float f32x4 __attribute__((ext_vector_type(4)));

#define LOG2E 1.44269504088896340736f

// ---- ws layout (float words) ---- (layout IDENTICAL to previous rounds)
// A-fragment packed weights: [tile16][kt][lane64][pl2][reg4] u32 words (pl=1 unused)
// Weights & biases PRE-SCALED: gate rows i,f,o by -log2e, gate g by +2*log2e.
// L0 x-chunk slot k==5 carries the L0 bias (bih+bhh); B-side stages 1.0 there.
#define OFF_E0 0
#define OFF_E1 24576
#define OFF_D0 57344
#define OFF_D1 81920
#define OFF_BE0 114688
#define OFF_BE1 114944
#define OFF_BD0 115200
#define OFF_BD1 115456
#define OFF_FCW 115712
#define OFF_FCB 115776
#define WS_TOT  115777

__device__ __forceinline__ float sig2(float g) {     // sigmoid(z), g = -log2e*z
    return __builtin_amdgcn_rcpf(1.0f + __builtin_amdgcn_exp2f(g));
}
__device__ __forceinline__ float tanh2(float g) {    // tanh(z), g = 2*log2e*z
    return 1.0f - 2.0f * __builtin_amdgcn_rcpf(1.0f + __builtin_amdgcn_exp2f(g));
}
__device__ __forceinline__ float tanhc(float c) {    // tanh(c), raw c
    return 1.0f - 2.0f * __builtin_amdgcn_rcpf(1.0f + __builtin_amdgcn_exp2f(c * (2.0f * LOG2E)));
}

// ---------------- prep: pack weights into MFMA A-fragment layout ----
__global__ void prep_kernel(
    const float* __restrict__ eWih0, const float* __restrict__ eWhh0,
    const float* __restrict__ ebih0, const float* __restrict__ ebhh0,
    const float* __restrict__ eWih1, const float* __restrict__ eWhh1,
    const float* __restrict__ ebih1, const float* __restrict__ ebhh1,
    const float* __restrict__ dWih0, const float* __restrict__ dWhh0,
    const float* __restrict__ dbih0, const float* __restrict__ dbhh0,
    const float* __restrict__ dWih1, const float* __restrict__ dWhh1,
    const float* __restrict__ dbih1, const float* __restrict__ dbhh1,
    const float* __restrict__ fcW,  const float* __restrict__ fcb,
    float* __restrict__ ws)
{
    int idx = blockIdx.x * blockDim.x + threadIdx.x;
    if (idx >= WS_TOT) return;
    float outv;
    if (idx < OFF_BE0) {
        int rel, nkt, xdim;
        const float *Wi, *Wh, *bi, *bh;
        if (idx < OFF_E1)      { rel = idx - OFF_E0; nkt = 3; xdim = IN_; Wi = eWih0; Wh = eWhh0; bi = ebih0; bh = ebhh0; }
        else if (idx < OFF_D0) { rel = idx - OFF_E1; nkt = 4; xdim = 64;  Wi = eWih1; Wh = eWhh1; bi = 0; bh = 0; }
        else if (idx < OFF_D1) { rel = idx - OFF_D0; nkt = 3; xdim = 1;   Wi = dWih0; Wh = dWhh0; bi = dbih0; bh = dbhh0; }
        else                   { rel = idx - OFF_D1; nkt = 4; xdim = 64;  Wi = dWih1; Wh = dWhh1; bi = 0; bh = 0; }
        int reg = rel & 3, pl = (rel >> 2) & 1, lane = (rel >> 3) & 63;
        int rest = rel >> 9;
        int kt = rest % nkt, mt = rest / nkt;
        int gp = mt * 16 + (lane & 15);
        int type = gp & 3;
        int j  = type * 64 + (gp >> 2);
        float sc = (type == 2) ? (2.0f * LOG2E) : (-LOG2E);
        union { f16 h2[2]; float f; } u_;
        #pragma unroll
        for (int h = 0; h < 2; ++h) {
            int k = kt * 32 + (lane >> 4) * 8 + reg * 2 + h;
            float v;
            if (nkt == 4)      v = (k < 64) ? Wi[j * 64 + k] : Wh[j * 64 + (k - 64)];
            else if (k < xdim) v = Wi[j * xdim + k];
            else if (k == 5)   v = bi[j] + bh[j];      // L0 bias in slot 5
            else if (k >= 32)  v = Wh[j * 64 + (k - 32)];
            else               v = 0.0f;
            v *= sc;
            f16 hi = (f16)v;
            u_.h2[h] = (pl == 0) ? hi : (f16)(v - (float)hi);
        }
        outv = u_.f;
    } else if (idx < OFF_FCW) {
        int rel = idx - OFF_BE0;
        int which = rel >> 8, gp = rel & 255;
        int type = gp & 3;
        int j = type * 64 + (gp >> 2);
        float sc = (type == 2) ? (2.0f * LOG2E) : (-LOG2E);
        const float *bi, *bh;
        if (which == 0)      { bi = ebih0; bh = ebhh0; }
        else if (which == 1) { bi = ebih1; bh = ebhh1; }
        else if (which == 2) { bi = dbih0; bh = dbhh0; }
        else                 { bi = dbih1; bh = dbhh1; }
        outv = (bi[j] + bh[j]) * sc;
    } else if (idx < OFF_FCB) {
        outv = fcW[idx - OFF_FCW];
    } else {
        outv = fcb[0];
    }
    ws[idx] = outv;
}

// LDS index helpers (f16 element index), ROWS=32 geometry
#define XBI(b,p,g,r)   ((((b)*2+(p))*4+(g))*GP + (r)*8)
#define HBI(b,p,k,g,r) (((((b)*2+(p))*2+(k))*4+(g))*GP + (r)*8)
#define XTOT (2*2*4*GP)      // 4096 f16
#define HHALF (2*2*4*GP)     // one buf of H0B/H1B: 4096 f16

#define MFMA(a,b,c) __builtin_amdgcn_mfma_f32_16x16x32_f16(a, b, c, 0, 0, 0)

__device__ __forceinline__ void stage_x5(f16* __restrict__ XB, int b, int r, const float* xv) {
    f16x8 ph, pl_;
    #pragma unroll
    for (int i = 0; i < 8; ++i) { ph[i] = (f16)0; pl_[i] = (f16)0; }
    #pragma unroll
    for (int i = 0; i < IN_; ++i) {
        f16 hh = (f16)xv[i]; ph[i] = hh; pl_[i] = (f16)(xv[i] - (float)hh);
    }
    ph[5] = (f16)1.0f;          // bias slot
    *(f16x8*)&XB[XBI(b,0,0,r)] = ph;
    *(f16x8*)&XB[XBI(b,1,0,r)] = pl_;
}
__device__ __forceinline__ void stage_x1(f16* __restrict__ XB, int b, int r, float v) {
    f16x8 ph, pl_;
    #pragma unroll
    for (int i = 0; i < 8; ++i) { ph[i] = (f16)0; pl_[i] = (f16)0; }
    f16 hh = (f16)v; ph[0] = hh; pl_[0] = (f16)(v - (float)hh);
    ph[5] = (f16)1.0f;          // bias slot
    *(f16x8*)&XB[XBI(b,0,0,r)] = ph;
    *(f16x8*)&XB[XBI(b,1,0,r)] = pl_;
}

// ---- standalone layer 0 (prologue + decoder): acc starts at 0 (bias in slot 5)
// 16-wave version: each wave owns ONE M-tile (tile = wave), u = wave*4 + g4.
__device__ __forceinline__ void layer0_only(
    int pX, int pH0r, int pH0w, int wave, int lane,
    const f16x8 (&wa)[7], float (&c0)[NT],
    const f16* __restrict__ XB, f16* __restrict__ H0B)
{
    const int g4 = lane >> 4, l15 = lane & 15;
    const int u = wave * 4 + g4;
    #pragma unroll
    for (int nt = 0; nt < NT; ++nt) {
        const int r = nt * 16 + l15;
        f16x8 xh  = *(const f16x8*)&XB [XBI(pX,0,g4,r)];
        f16x8 xl  = *(const f16x8*)&XB [XBI(pX,1,g4,r)];
        f16x8 hh0 = *(const f16x8*)&H0B[HBI(pH0r,0,0,g4,r)];
        f16x8 hl0 = *(const f16x8*)&H0B[HBI(pH0r,1,0,g4,r)];
        f16x8 hh1 = *(const f16x8*)&H0B[HBI(pH0r,0,1,g4,r)];
        f16x8 hl1 = *(const f16x8*)&H0B[HBI(pH0r,1,1,g4,r)];
        f32x4 z = {0.0f, 0.0f, 0.0f, 0.0f};
        z = MFMA(wa[0], xh,  z);
        z = MFMA(wa[0], xl,  z);
        z = MFMA(wa[1], hh0, z);
        z = MFMA(wa[1], hl0, z);
        z = MFMA(wa[2], hh1, z);
        z = MFMA(wa[2], hl1, z);
        float ig = sig2(z[0]), fg = sig2(z[1]);
        float gg = tanh2(z[2]), og = sig2(z[3]);
        float c = fmaf(fg, c0[nt], ig * gg);
        c0[nt] = c;
        float h = og * tanhc(c);
        f16 hh = (f16)h, hl = (f16)(h - (float)hh);
        H0B[HBI(pH0w,0,(u>>5),(u>>3)&3,r) + (u&7)] = hh;
        H0B[HBI(pH0w,1,(u>>5),(u>>3)&3,r) + (u&7)] = hl;
    }
}

// ---- standalone layer 1 (epilogue + decoder)
template<bool DEC>
__device__ __forceinline__ void layer1_only(
    int pH0, int pH1r, int pH1w, int wave, int lane,
    const f16x8 (&wa)[7], const f32x4 b1, float (&c1)[NT],
    const f16* __restrict__ H0B, f16* __restrict__ H1B, float* __restrict__ H1F)
{
    const int g4 = lane >> 4, l15 = lane & 15;
    const int u = wave * 4 + g4;
    #pragma unroll
    for (int nt = 0; nt < NT; ++nt) {
        const int r = nt * 16 + l15;
        f16x8 hh0 = *(const f16x8*)&H0B[HBI(pH0,0,0,g4,r)];
        f16x8 hl0 = *(const f16x8*)&H0B[HBI(pH0,1,0,g4,r)];
        f16x8 hh1 = *(const f16x8*)&H0B[HBI(pH0,0,1,g4,r)];
        f16x8 hl1 = *(const f16x8*)&H0B[HBI(pH0,1,1,g4,r)];
        f16x8 gh0 = *(const f16x8*)&H1B[HBI(pH1r,0,0,g4,r)];
        f16x8 gl0 = *(const f16x8*)&H1B[HBI(pH1r,1,0,g4,r)];
        f16x8 gh1 = *(const f16x8*)&H1B[HBI(pH1r,0,1,g4,r)];
        f16x8 gl1 = *(const f16x8*)&H1B[HBI(pH1r,1,1,g4,r)];
        f32x4 a = b1;
        a = MFMA(wa[3], hh0, a);
        a = MFMA(wa[3], hl0, a);
        a = MFMA(wa[4], hh1, a);
        a = MFMA(wa[4], hl1, a);
        a = MFMA(wa[5], gh0, a);
        a = MFMA(wa[5], gl0, a);
        a = MFMA(wa[6], gh1, a);
        a = MFMA(wa[6], gl1, a);
        float ig = sig2(a[0]), fg = sig2(a[1]);
        float gg = tanh2(a[2]), og = sig2(a[3]);
        float c = fmaf(fg, c1[nt], ig * gg);
        c1[nt] = c;
        float h = og * tanhc(c);
        f16 hh = (f16)h, hl = (f16)(h - (float)hh);
        H1B[HBI(pH1w,0,(u>>5),(u>>3)&3,r) + (u&7)] = hh;
        H1B[HBI(pH1w,1,(u>>5),(u>>3)&3,r) + (u&7)] = hl;
        if (DEC) H1F[u * 33 + r] = h;
    }
}

// ---- fused encoder phase t: {L1_t ; L0_{t+1}} — ONE barrier per timestep.
// p = t&1. h0_t in H0B[p]; h1_{t-1} in H1B[p^1]; x_{t+1} in XB[p^1].
// Writes h1_t -> H1B[p], h0_{t+1} -> H0B[p^1]. L1 and L0 SHARE the h0_t frags.
// The two MFMA chains (a = L1_t, z = L0_{t+1}) are INDEPENDENT and issued
// interleaved -> 2 acc streams/wave x 4 waves/SIMD = 8 streams hide MFMA latency.
// Activation bundles for both layers also interleaved (trans-pipe ILP).
__device__ __forceinline__ void enc_phase(
    int p, int wave, int lane,
    const f16x8 (&wa)[7], const f32x4 b1,
    float (&c0)[NT], float (&c1)[NT],
    const f16* __restrict__ XB, f16* __restrict__ H0B, f16* __restrict__ H1B)
{
    const int g4 = lane >> 4, l15 = lane & 15;
    const int q = p ^ 1;
    const int u = wave * 4 + g4;
    #pragma unroll
    for (int nt = 0; nt < NT; ++nt) {
        const int r = nt * 16 + l15;
        f16x8 hh0 = *(const f16x8*)&H0B[HBI(p,0,0,g4,r)];   // h0_t (shared L1/L0)
        f16x8 hl0 = *(const f16x8*)&H0B[HBI(p,1,0,g4,r)];
        f16x8 hh1 = *(const f16x8*)&H0B[HBI(p,0,1,g4,r)];
        f16x8 hl1 = *(const f16x8*)&H0B[HBI(p,1,1,g4,r)];
        f16x8 gh0 = *(const f16x8*)&H1B[HBI(q,0,0,g4,r)];   // h1_{t-1}
        f16x8 gl0 = *(const f16x8*)&H1B[HBI(q,1,0,g4,r)];
        f16x8 gh1 = *(const f16x8*)&H1B[HBI(q,0,1,g4,r)];
        f16x8 gl1 = *(const f16x8*)&H1B[HBI(q,1,1,g4,r)];
        f16x8 xh  = *(const f16x8*)&XB [XBI(q,0,g4,r)];     // x_{t+1}
        f16x8 xl  = *(const f16x8*)&XB [XBI(q,1,g4,r)];
        // ---- interleaved MFMA: a = L1_t gates, z = L0_{t+1} gates ----
        f32x4 a = b1;
        f32x4 z = {0.0f, 0.0f, 0.0f, 0.0f};
        a = MFMA(wa[3], hh0, a);  z = MFMA(wa[0], xh,  z);
        a = MFMA(wa[3], hl0, a);  z = MFMA(wa[0], xl,  z);
        a = MFMA(wa[4], hh1, a);  z = MFMA(wa[1], hh0, z);
        a = MFMA(wa[4], hl1, a);  z = MFMA(wa[1], hl0, z);
        a = MFMA(wa[5], gh0, a);  z = MFMA(wa[2], hh1, z);
        a = MFMA(wa[5], gl0, a);  z = MFMA(wa[2], hl1, z);
        a = MFMA(wa[6], gh1, a);
        a = MFMA(wa[6], gl1, a);
        // ---- interleaved activations (independent bundles) ----
        float ia = sig2(a[0]), iz = sig2(z[0]);
        float fa = sig2(a[1]), fz = sig2(z[1]);
        float ga = tanh2(a[2]), gz = tanh2(z[2]);
        float oa = sig2(a[3]), oz = sig2(z[3]);
        float ca = fmaf(fa, c1[nt], ia * ga); c1[nt] = ca;
        float cz = fmaf(fz, c0[nt], iz * gz); c0[nt] = cz;
        float ha = oa * tanhc(ca);
        float hz = oz * tanhc(cz);
        f16 hah = (f16)ha, hal = (f16)(ha - (float)hah);
        f16 hzh = (f16)hz, hzl = (f16)(hz - (float)hzh);
        H1B[HBI(p,0,(u>>5),(u>>3)&3,r) + (u&7)] = hah;
        H1B[HBI(p,1,(u>>5),(u>>3)&3,r) + (u&7)] = hal;
        H0B[HBI(q,0,(u>>5),(u>>3)&3,r) + (u&7)] = hzh;
        H0B[HBI(q,1,(u>>5),(u>>3)&3,r) + (u&7)] = hzl;
    }
}

// 1024 threads = 16 waves; wave w owns M-tile w (units 4w..4w+3); ROWS=32
// batch rows/block; grid = 512. 16 waves = 4 waves/SIMD in ONE block ->
// 4 independent instruction streams per SIMD overlap MFMA/trans/LDS pipes
// (R6 showed 2 separate 8-wave blocks never co-schedule; this forces it
// within one block). launch_bounds(1024) caps VGPR at 128; mt=1 live set
// ~100 regs so no spill (R4 lesson: never force below the live set).
__global__ __launch_bounds__(1024) void lstm_kernel(
    const float* __restrict__ src, const float* __restrict__ ws,
    float* __restrict__ out)
{
    __shared__ __align__(16) f16 XB [XTOT];           // 8 KB
    __shared__ __align__(16) f16 H0B[2*HHALF];        // 16 KB
    __shared__ __align__(16) f16 H1B[2*HHALF];        // 16 KB
    __shared__ float H1F[64*33];                      // 8.25 KB (decoder fc)
    __shared__ float FCW[64];

    const int tid  = threadIdx.x;
    const int lane = tid & 63;
    const int wave = __builtin_amdgcn_readfirstlane(tid >> 6);
    const int g4   = lane >> 4;
    const int rowBase = blockIdx.x * ROWS;

    float c0[NT], c1[NT];
    #pragma unroll
    for (int nt = 0; nt < NT; ++nt) { c0[nt] = 0.0f; c1[nt] = 0.0f; }

    f16x8 wa[7];                // [kt: 0-2 L0, 3-6 L1], hi plane only, tile = wave
    f32x4 b1;

    auto ldw = [&](int off0, int off1, int ob1) {
        #pragma unroll
        for (int kt = 0; kt < 3; ++kt)
            wa[kt] = *(const f16x8*)(ws + off0 + ((wave * 3 + kt) * 64 + lane) * 8);
        #pragma unroll
        for (int kt = 0; kt < 4; ++kt)
            wa[3 + kt] = *(const f16x8*)(ws + off1 + ((wave * 4 + kt) * 64 + lane) * 8);
        b1 = *(const f32x4*)(ws + ob1 + wave * 16 + g4 * 4);
    };
    ldw(OFF_E0, OFF_E1, OFF_BE1);

    // zero XB (fully) and parity-1 halves of H0B/H1B (h0_{-1} = h1_{-1} = 0)
    for (int i = tid; i < XTOT; i += 1024) XB[i] = (f16)0;
    for (int i = tid; i < HHALF; i += 1024) { H0B[HHALF + i] = (f16)0; H1B[HHALF + i] = (f16)0; }
    if (tid < 64) FCW[tid] = ws[OFF_FCW + tid];
    const float fcbv = ws[OFF_FCB];

    const int xr = lane & (ROWS - 1);
    const float* sp = src + (size_t)(rowBase + xr) * (S_ * IN_);
    __syncthreads();

    // stage x0 -> XB[0], x1 -> XB[1]
    if (wave == 15 && lane < ROWS) {
        float xv[IN_];
        #pragma unroll
        for (int i = 0; i < IN_; ++i) xv[i] = sp[i];
        stage_x5(XB, 0, lane, xv);
        #pragma unroll
        for (int i = 0; i < IN_; ++i) xv[i] = sp[IN_ + i];
        stage_x5(XB, 1, lane, xv);
    }
    __syncthreads();

    // prologue: L0_0 (reads XB[0], H0B[1](=0), writes H0B[0])
    layer0_only(0, 1, 0, wave, lane, wa, c0, XB, H0B);
    __syncthreads();

    // ---------------- encoder: fused phases, ONE barrier per timestep ----------
    #pragma unroll 1
    for (int t = 0; t < S_ - 1; ++t) {
        const int p = t & 1;
        float xv[IN_];
        const bool pf = (wave == 15) && (lane < ROWS) && (t + 2 < S_);
        if (pf) {
            #pragma unroll
            for (int i = 0; i < IN_; ++i) xv[i] = sp[(t + 2) * IN_ + i];
        }
        enc_phase(p, wave, lane, wa, b1, c0, c1, XB, H0B, H1B);
        if (pf) stage_x5(XB, p, lane, xv);   // x_{t+2} -> XB[(t+2)&1] = XB[p]
        __syncthreads();
    }

    // epilogue: L1_{S-1} (reads H0B[1], H1B[0], writes H1B[1])
    layer1_only<false>(1, 0, 1, wave, lane, wa, b1, c1, H0B, H1B, H1F);
    __syncthreads();

    // ---------------- decoder ----------------
    ldw(OFF_D0, OFF_D1, OFF_BD1);
    if (wave == 15 && lane < ROWS) stage_x1(XB, 0, lane, sp[(S_ - 1) * IN_ + 3]);
    __syncthreads();

    #pragma unroll 1
    for (int t = 0; t < T_; ++t) {
        const int q = t & 1;
        layer0_only(q, q ^ 1, q, wave, lane, wa, c0, XB, H0B);
        __syncthreads();
        layer1_only<true>(q, q ^ 1, q, wave, lane, wa, b1, c1, H0B, H1B, H1F);
        __syncthreads();
        if (wave == 0 && lane < ROWS) {   // fc head (lane = row)
            float pv = fcbv;
            #pragma unroll 4
            for (int k = 0; k < 64; ++k) pv = fmaf(FCW[k], H1F[k * 33 + lane], pv);
            out[(size_t)(rowBase + lane) * T_ + t] = pv;
            if (t + 1 < T_) stage_x1(XB, q ^ 1, lane, pv);
        }
        __syncthreads();
    }
}

extern "C" void kernel_launch(void* const* d_in, const int* in_sizes, int n_in,
                              void* d_out, int out_size, void* d_ws, size_t ws_size,
                              hipStream_t stream)
{
    const float* src = (const float*)d_in[0];
    float* ws  = (float*)d_ws;
    float* out = (float*)d_out;

    prep_kernel<<<(WS_TOT + 255) / 256, 256, 0, stream>>>(
        (const float*)d_in[1],  (const float*)d_in[2],
        (const float*)d_in[3],  (const float*)d_in[4],
        (const float*)d_in[5],  (const float*)d_in[6],
        (const float*)d_in[7],  (const float*)d_in[8],
        (const float*)d_in[9],  (const float*)d_in[10],
        (const float*)d_in[11], (const float*)d_in[12],
        (const float*)d_in[13], (const float*)d_in[14],
        (const float*)d_in[15], (const float*)d_in[16],
        (const float*)d_in[17], (const float*)d_in[18],
        ws);

    lstm_kernel<<<B_ / ROWS, 1024, 0, stream>>>(src, ws, out);
}

// Round 8
// 1628.293 us; speedup vs baseline: 2.3373x; 1.0349x over previous
//
#include <hip/hip_runtime.h>
#include <stdint.h>

#define B_ 16384
#define S_ 336
#define T_ 48
#define IN_ 5
#define H_ 64

#define ROWS 64              // batch rows per block (one 32-row tile per rt)

typedef _Float16 f16;
typedef _Float16 f16x8 __attribute__((ext_vector_type(8)));
typedef float f32x16 __attribute__((ext_vector_type(16)));

#define LOG2E 1.44269504088896340736f

// ---- ws layout (f32 words) ----
// 32x32x16 A-fragments: [gt8][kc][lane64][w4] u32 words, f16 single plane.
// Weights & biases PRE-SCALED: gate rows i,f,o by -log2e, gate g by +2*log2e.
// L0 chunk0: x at k0..4, bias at k5. L1 chunk8: bias at k0 (B-side one-hot).
#define NKC0 5
#define NKC1 9
#define OFF_E0 0                         // 8*5*256 = 10240
#define OFF_E1 10240                     // 8*9*256 = 18432
#define OFF_D0 28672
#define OFF_D1 38912                     // ends 57344
#define OFF_FCW 57344
#define OFF_FCB 57408
#define WS_TOT  57409

__device__ __forceinline__ float sig2(float g) {     // sigmoid(z), g = -log2e*z
    return __builtin_amdgcn_rcpf(1.0f + __builtin_amdgcn_exp2f(g));
}
__device__ __forceinline__ float tanh2(float g) {    // tanh(z), g = 2*log2e*z
    return 1.0f - 2.0f * __builtin_amdgcn_rcpf(1.0f + __builtin_amdgcn_exp2f(g));
}
__device__ __forceinline__ float tanhc(float c) {    // tanh(c), raw c
    return 1.0f - 2.0f * __builtin_amdgcn_rcpf(1.0f + __builtin_amdgcn_exp2f(c * (2.0f * LOG2E)));
}

// ---------------- prep: pack weights into 32x32x16 A-fragment layout ----
// A elem (gt,kc,lane,w,hf): gate row gr = lane&31 (= q*4+type, q=unit-in-tile),
// j = type*64 + gt*8 + q; k_local = (lane>>5)*8 + w*2 + hf.
__global__ void prep_kernel(
    const float* __restrict__ eWih0, const float* __restrict__ eWhh0,
    const float* __restrict__ ebih0, const float* __restrict__ ebhh0,
    const float* __restrict__ eWih1, const float* __restrict__ eWhh1,
    const float* __restrict__ ebih1, const float* __restrict__ ebhh1,
    const float* __restrict__ dWih0, const float* __restrict__ dWhh0,
    const float* __restrict__ dbih0, const float* __restrict__ dbhh0,
    const float* __restrict__ dWih1, const float* __restrict__ dWhh1,
    const float* __restrict__ dbih1, const float* __restrict__ dbhh1,
    const float* __restrict__ fcW,  const float* __restrict__ fcb,
    float* __restrict__ ws)
{
    int idx = blockIdx.x * blockDim.x + threadIdx.x;
    if (idx >= WS_TOT) return;
    float outv;
    if (idx < OFF_FCW) {
        int off, nkc, which;
        if (idx < OFF_E1)      { off = OFF_E0; nkc = NKC0; which = 0; }
        else if (idx < OFF_D0) { off = OFF_E1; nkc = NKC1; which = 1; }
        else if (idx < OFF_D1) { off = OFF_D0; nkc = NKC0; which = 2; }
        else                   { off = OFF_D1; nkc = NKC1; which = 3; }
        int rel = idx - off;
        int w = rel & 3, lane = (rel >> 2) & 63;
        int rest = rel >> 8;
        int kc = rest % nkc, gt = rest / nkc;
        int gr = lane & 31;
        int q = gr >> 2, type = gr & 3;
        int j = type * 64 + gt * 8 + q;
        float sc = (type == 2) ? (2.0f * LOG2E) : (-LOG2E);
        union { f16 h2[2]; float f; } u_;
        #pragma unroll
        for (int hf = 0; hf < 2; ++hf) {
            int kl = (lane >> 5) * 8 + w * 2 + hf;
            float v = 0.0f;
            if (which == 0) {            // enc L0
                if (kc == 0) {
                    if (kl < IN_)      v = eWih0[j * IN_ + kl];
                    else if (kl == 5)  v = ebih0[j] + ebhh0[j];
                } else                   v = eWhh0[j * 64 + (kc - 1) * 16 + kl];
            } else if (which == 1) {     // enc L1
                if (kc < 4)            v = eWih1[j * 64 + kc * 16 + kl];
                else if (kc < 8)       v = eWhh1[j * 64 + (kc - 4) * 16 + kl];
                else if (kl == 0)      v = ebih1[j] + ebhh1[j];   // bias chunk
            } else if (which == 2) {     // dec L0
                if (kc == 0) {
                    if (kl == 0)       v = dWih0[j];
                    else if (kl == 5)  v = dbih0[j] + dbhh0[j];
                } else                   v = dWhh0[j * 64 + (kc - 1) * 16 + kl];
            } else {                     // dec L1
                if (kc < 4)            v = dWih1[j * 64 + kc * 16 + kl];
                else if (kc < 8)       v = dWhh1[j * 64 + (kc - 4) * 16 + kl];
                else if (kl == 0)      v = dbih1[j] + dbhh1[j];
            }
            u_.h2[hf] = (f16)(v * sc);
        }
        outv = u_.f;
    } else if (idx < OFF_FCB) {
        outv = fcW[idx - OFF_FCW];
    } else {
        outv = fcb[0];
    }
    ws[idx] = outv;
}

// LDS layouts (f16 element index). B-frag read: lane l -> hf = l>>5,
// col/row = rt*32 + (l&31); k = kc*16 + hf*8 + j.
__device__ __forceinline__ int xbi(int b, int pl, int hf, int row) {
    return ((((b * 2 + pl) * 2 + hf) * 64) + row) * 8;
}
__device__ __forceinline__ int hbi(int b, int pl, int kc, int hf, int row) {
    return (((((b * 2 + pl) * 4 + kc) * 2 + hf) * 64) + row) * 8;
}
#define XTOT  (2*2*2*64*8)     // 4096 f16 = 8 KB
#define HTOT  (2*2*4*2*64*8)   // 16384 f16 = 32 KB
#define HHALF (2*4*2*64*8)     // one buf = 8192 f16
#define PLSTR (4*2*64*8)       // pl stride within buf = 4096 f16

#define MFMA32(a,b,c) __builtin_amdgcn_mfma_f32_32x32x16_f16(a, b, c, 0, 0, 0)

__device__ __forceinline__ void stage_x5(f16* __restrict__ XB, int b, int r, const float* xv) {
    f16x8 ph = {}, pl_ = {}, zz = {};
    #pragma unroll
    for (int i = 0; i < IN_; ++i) {
        f16 hh = (f16)xv[i]; ph[i] = hh; pl_[i] = (f16)(xv[i] - (float)hh);
    }
    ph[5] = (f16)1.0f;          // bias slot (k=5)
    *(f16x8*)&XB[xbi(b,0,0,r)] = ph;
    *(f16x8*)&XB[xbi(b,0,1,r)] = zz;
    *(f16x8*)&XB[xbi(b,1,0,r)] = pl_;
    *(f16x8*)&XB[xbi(b,1,1,r)] = zz;
}
__device__ __forceinline__ void stage_x1(f16* __restrict__ XB, int b, int r, float v) {
    f16x8 ph = {}, pl_ = {}, zz = {};
    f16 hh = (f16)v; ph[0] = hh; pl_[0] = (f16)(v - (float)hh);
    ph[5] = (f16)1.0f;
    *(f16x8*)&XB[xbi(b,0,0,r)] = ph;
    *(f16x8*)&XB[xbi(b,0,1,r)] = zz;
    *(f16x8*)&XB[xbi(b,1,0,r)] = pl_;
    *(f16x8*)&XB[xbi(b,1,1,r)] = zz;
}

// activation+store for one bundle (unit qi of this wave's tile).
// acc regs 4qi..4qi+3 = gates i,f,g,o of unit u = gt*8 + 2*qi + hf, col = row.
__device__ __forceinline__ void act_store(
    float gi, float gf, float gg_, float go, float& c, int qi,
    int gt, int hf, int row, int b, f16* __restrict__ H, float* __restrict__ H1F)
{
    float ig = sig2(gi), fg = sig2(gf);
    float gg = tanh2(gg_), og = sig2(go);
    float cc = fmaf(fg, c, ig * gg);
    c = cc;
    float h = og * tanhc(cc);
    f16 hh = (f16)h, hl = (f16)(h - (float)hh);
    int u = gt * 8 + 2 * qi + hf;
    int base = hbi(b, 0, u >> 4, (u >> 3) & 1, row) + (u & 7);
    H[base] = hh;
    H[base + PLSTR] = hl;
    if (H1F) H1F[u * 65 + row] = h;
}

// ---- standalone layer 0 (prologue + decoder): z = W0 @ [x|h0_prev], bias in x k5
__device__ __forceinline__ void layer0_only(
    int pX, int pH0r, int pH0w, int gt, int hf, int row,
    const f16x8 (&wa0)[NKC0], float (&c0)[4],
    const f16* __restrict__ XB, f16* __restrict__ H0B)
{
    f32x16 z = {};
    #pragma unroll
    for (int kc = 0; kc < 4; ++kc) {
        f16x8 hh = *(const f16x8*)&H0B[hbi(pH0r,0,kc,hf,row)];
        f16x8 hl = *(const f16x8*)&H0B[hbi(pH0r,1,kc,hf,row)];
        z = MFMA32(wa0[1+kc], hh, z);
        z = MFMA32(wa0[1+kc], hl, z);
    }
    {
        f16x8 xh = *(const f16x8*)&XB[xbi(pX,0,hf,row)];
        f16x8 xl = *(const f16x8*)&XB[xbi(pX,1,hf,row)];
        z = MFMA32(wa0[0], xh, z);
        z = MFMA32(wa0[0], xl, z);
    }
    #pragma unroll
    for (int qi = 0; qi < 4; ++qi)
        act_store(z[4*qi], z[4*qi+1], z[4*qi+2], z[4*qi+3], c0[qi], qi,
                  gt, hf, row, pH0w, H0B, nullptr);
}

// ---- standalone layer 1 (epilogue + decoder): a = W1 @ [h0|h1_prev] + bias chunk
template<bool DEC>
__device__ __forceinline__ void layer1_only(
    int pH0, int pH1r, int pH1w, int gt, int hf, int row,
    const f16x8 (&wa1)[NKC1], f16x8 bvec, float (&c1)[4],
    const f16* __restrict__ H0B, f16* __restrict__ H1B, float* __restrict__ H1F)
{
    f32x16 a = {};
    a = MFMA32(wa1[8], bvec, a);            // bias (B one-hot at k0)
    #pragma unroll
    for (int kc = 0; kc < 4; ++kc) {
        f16x8 hh = *(const f16x8*)&H0B[hbi(pH0,0,kc,hf,row)];
        f16x8 hl = *(const f16x8*)&H0B[hbi(pH0,1,kc,hf,row)];
        a = MFMA32(wa1[kc], hh, a);
        a = MFMA32(wa1[kc], hl, a);
    }
    #pragma unroll
    for (int kc = 0; kc < 4; ++kc) {
        f16x8 gh = *(const f16x8*)&H1B[hbi(pH1r,0,kc,hf,row)];
        f16x8 gl = *(const f16x8*)&H1B[hbi(pH1r,1,kc,hf,row)];
        a = MFMA32(wa1[4+kc], gh, a);
        a = MFMA32(wa1[4+kc], gl, a);
    }
    #pragma unroll
    for (int qi = 0; qi < 4; ++qi)
        act_store(a[4*qi], a[4*qi+1], a[4*qi+2], a[4*qi+3], c1[qi], qi,
                  gt, hf, row, pH1w, H1B, DEC ? H1F : nullptr);
}

// ---- fused encoder phase t: {L1_t ; L0_{t+1}} — ONE barrier per timestep.
// h0_t frags read ONCE, shared by both chains. z-act bundles interleaved
// between the a-chain's h1 MFMA chunks (independent -> fills issue stream).
__device__ __forceinline__ void enc_phase(
    int p, int gt, int hf, int row,
    const f16x8 (&wa0)[NKC0], const f16x8 (&wa1)[NKC1], f16x8 bvec,
    float (&c0)[4], float (&c1)[4],
    const f16* __restrict__ XB, f16* __restrict__ H0B, f16* __restrict__ H1B)
{
    const int q = p ^ 1;
    f32x16 a = {};
    f32x16 z = {};
    a = MFMA32(wa1[8], bvec, a);            // L1 bias
    #pragma unroll
    for (int kc = 0; kc < 4; ++kc) {        // shared h0_t chunks
        f16x8 hh = *(const f16x8*)&H0B[hbi(p,0,kc,hf,row)];
        f16x8 hl = *(const f16x8*)&H0B[hbi(p,1,kc,hf,row)];
        a = MFMA32(wa1[kc], hh, a);
        a = MFMA32(wa1[kc], hl, a);
        z = MFMA32(wa0[1+kc], hh, z);
        z = MFMA32(wa0[1+kc], hl, z);
    }
    {                                        // x_{t+1} chunk -> z complete
        f16x8 xh = *(const f16x8*)&XB[xbi(q,0,hf,row)];
        f16x8 xl = *(const f16x8*)&XB[xbi(q,1,hf,row)];
        z = MFMA32(wa0[0], xh, z);
        z = MFMA32(wa0[0], xl, z);
    }
    #pragma unroll
    for (int kc = 0; kc < 4; ++kc) {        // h1_{t-1} chunks; z-acts interleave
        f16x8 gh = *(const f16x8*)&H1B[hbi(q,0,kc,hf,row)];
        f16x8 gl = *(const f16x8*)&H1B[hbi(q,1,kc,hf,row)];
        a = MFMA32(wa1[4+kc], gh, a);
        a = MFMA32(wa1[4+kc], gl, a);
        act_store(z[4*kc], z[4*kc+1], z[4*kc+2], z[4*kc+3], c0[kc], kc,
                  gt, hf, row, q, H0B, nullptr);
    }
    #pragma unroll
    for (int qi = 0; qi < 4; ++qi)
        act_store(a[4*qi], a[4*qi+1], a[4*qi+2], a[4*qi+3], c1[qi], qi,
                  gt, hf, row, p, H1B, nullptr);
}

// 1024 threads = 16 waves; wave = gt*2 + rt owns one 32-gate x 32-row tile of
// BOTH L1_t and L0_{t+1} (shared h0 frags). ROWS=64/block, grid=256 (1/CU).
// 32x32x16 MFMA: -20% matrix-pipe cycles, half the MFMA instructions, and
// -55% LDS read traffic vs the 16x16 structure (R7).
__global__ __launch_bounds__(1024) void lstm_kernel(
    const float* __restrict__ src, const float* __restrict__ ws,
    float* __restrict__ out)
{
    __shared__ __align__(16) f16 XB [XTOT];   // 8 KB
    __shared__ __align__(16) f16 H0B[HTOT];   // 32 KB
    __shared__ __align__(16) f16 H1B[HTOT];   // 32 KB
    __shared__ float H1F[64 * 65];            // 16.25 KB (decoder fc)
    __shared__ float FCW[64];

    const int tid  = threadIdx.x;
    const int lane = tid & 63;
    const int wave = __builtin_amdgcn_readfirstlane(tid >> 6);
    const int gt   = wave >> 1;
    const int rt   = wave & 1;
    const int hf   = lane >> 5;
    const int row  = rt * 32 + (lane & 31);
    const int rowBase = blockIdx.x * ROWS;

    float c0[4], c1[4];
    #pragma unroll
    for (int i = 0; i < 4; ++i) { c0[i] = 0.0f; c1[i] = 0.0f; }

    f16x8 wa0[NKC0], wa1[NKC1];
    f16x8 bvec = {};
    if (hf == 0) bvec[0] = (f16)1.0f;   // one-hot B for the bias chunk (k=0)

    auto ldw = [&](int off0, int off1) {
        #pragma unroll
        for (int kc = 0; kc < NKC0; ++kc)
            wa0[kc] = *(const f16x8*)(ws + off0 + ((gt * NKC0 + kc) * 64 + lane) * 4);
        #pragma unroll
        for (int kc = 0; kc < NKC1; ++kc)
            wa1[kc] = *(const f16x8*)(ws + off1 + ((gt * NKC1 + kc) * 64 + lane) * 4);
    };
    ldw(OFF_E0, OFF_E1);

    // zero parity-1 halves of H0B/H1B (h0_{-1} = h1_{-1} = 0)
    for (int i = tid; i < HHALF; i += 1024) { H0B[HHALF + i] = (f16)0; H1B[HHALF + i] = (f16)0; }
    if (tid < 64) FCW[tid] = ws[OFF_FCW + tid];
    const float fcbv = ws[OFF_FCB];

    const float* sp = src + (size_t)(rowBase + lane) * (S_ * IN_);
    __syncthreads();

    // stage x0 -> XB[0], x1 -> XB[1] (wave 15: lane = row, 64 rows)
    if (wave == 15) {
        float xv[IN_];
        #pragma unroll
        for (int i = 0; i < IN_; ++i) xv[i] = sp[i];
        stage_x5(XB, 0, lane, xv);
        #pragma unroll
        for (int i = 0; i < IN_; ++i) xv[i] = sp[IN_ + i];
        stage_x5(XB, 1, lane, xv);
    }
    __syncthreads();

    // prologue: L0_0 (reads XB[0], H0B[1](=0), writes H0B[0])
    layer0_only(0, 1, 0, gt, hf, row, wa0, c0, XB, H0B);
    __syncthreads();

    // ---------------- encoder: fused phases, ONE barrier per timestep ----------
    #pragma unroll 1
    for (int t = 0; t < S_ - 1; ++t) {
        const int p = t & 1;
        float xv[IN_];
        const bool pf = (wave == 15) && (t + 2 < S_);
        if (pf) {
            #pragma unroll
            for (int i = 0; i < IN_; ++i) xv[i] = sp[(t + 2) * IN_ + i];
        }
        enc_phase(p, gt, hf, row, wa0, wa1, bvec, c0, c1, XB, H0B, H1B);
        if (pf) stage_x5(XB, p, lane, xv);   // x_{t+2} -> XB[(t+2)&1] = XB[p]
        __syncthreads();
    }

    // epilogue: L1_{S-1} (reads H0B[1], H1B[0], writes H1B[1])
    layer1_only<false>(1, 0, 1, gt, hf, row, wa1, bvec, c1, H0B, H1B, H1F);
    __syncthreads();

    // ---------------- decoder ----------------
    ldw(OFF_D0, OFF_D1);
    if (wave == 15) stage_x1(XB, 0, lane, sp[(S_ - 1) * IN_ + 3]);   // dec_in0
    __syncthreads();

    #pragma unroll 1
    for (int t = 0; t < T_; ++t) {
        const int q = t & 1;
        layer0_only(q, q ^ 1, q, gt, hf, row, wa0, c0, XB, H0B);
        __syncthreads();
        layer1_only<true>(q, q ^ 1, q, gt, hf, row, wa1, bvec, c1, H0B, H1B, H1F);
        __syncthreads();
        if (wave == 0) {   // fc head: pred = fcW . h1_new + fcb  (lane = row)
            float pv = fcbv;
            #pragma unroll 8
            for (int k = 0; k < 64; ++k) pv = fmaf(FCW[k], H1F[k * 65 + lane], pv);
            out[(size_t)(rowBase + lane) * T_ + t] = pv;
            if (t + 1 < T_) stage_x1(XB, q ^ 1, lane, pv);
        }
        __syncthreads();
    }
}

extern "C" void kernel_launch(void* const* d_in, const int* in_sizes, int n_in,
                              void* d_out, int out_size, void* d_ws, size_t ws_size,
                              hipStream_t stream)
{
    const float* src = (const float*)d_in[0];
    float* ws  = (float*)d_ws;
    float* out = (float*)d_out;

    prep_kernel<<<(WS_TOT + 255) / 256, 256, 0, stream>>>(
        (const float*)d_in[1],  (const float*)d_in[2],
        (const float*)d_in[3],  (const float*)d_in[4],
        (const float*)d_in[5],  (const float*)d_in[6],
        (const float*)d_in[7],  (const float*)d_in[8],
        (const float*)d_in[9],  (const float*)d_in[10],
        (const float*)d_in[11], (const float*)d_in[12],
        (const float*)d_in[13], (const float*)d_in[14],
        (const float*)d_in[15], (const float*)d_in[16],
        (const float*)d_in[17], (const float*)d_in[18],
        ws);

    lstm_kernel<<<B_ / ROWS, 1024, 0, stream>>>(src, ws, out);
}

// Round 9
// 1621.118 us; speedup vs baseline: 2.3476x; 1.0044x over previous
//
#include <hip/hip_runtime.h>
#include <stdint.h>

#define B_ 16384
#define S_ 336
#define T_ 48
#define IN_ 5
#define H_ 64

#define ROWS 64              // batch rows per block (one 32-row tile per rt)

typedef _Float16 f16;
typedef _Float16 f16x8 __attribute__((ext_vector_type(8)));
typedef float f32x16 __attribute__((ext_vector_type(16)));

#define LOG2E 1.44269504088896340736f

// ---- ws layout (f32 words) ----
// 32x32x16 A-fragments: [gt8][kc][lane64][w4] u32 words, f16 single plane.
// Weights & biases PRE-SCALED: gate rows i,f,o by -log2e, gate g by +2*log2e.
// L0 chunk0: x at k0..4, bias at k5. L1 chunk8: bias at k0 (B-side one-hot).
#define NKC0 5
#define NKC1 9
#define OFF_E0 0                         // 8*5*256 = 10240
#define OFF_E1 10240                     // 8*9*256 = 18432
#define OFF_D0 28672
#define OFF_D1 38912                     // ends 57344
#define OFF_FCW 57344
#define OFF_FCB 57408
#define WS_TOT  57409

__device__ __forceinline__ float sig2(float g) {     // sigmoid(z), g = -log2e*z
    return __builtin_amdgcn_rcpf(1.0f + __builtin_amdgcn_exp2f(g));
}
__device__ __forceinline__ float tanh2(float g) {    // tanh(z), g = 2*log2e*z
    return 1.0f - 2.0f * __builtin_amdgcn_rcpf(1.0f + __builtin_amdgcn_exp2f(g));
}
__device__ __forceinline__ float tanhc(float c) {    // tanh(c), raw c
    return 1.0f - 2.0f * __builtin_amdgcn_rcpf(1.0f + __builtin_amdgcn_exp2f(c * (2.0f * LOG2E)));
}

// ---------------- prep: pack weights into 32x32x16 A-fragment layout ----
// A elem (gt,kc,lane,w,hf): gate row gr = lane&31 (= q*4+type, q=unit-in-tile),
// j = type*64 + gt*8 + q; k_local = (lane>>5)*8 + w*2 + hf.
__global__ void prep_kernel(
    const float* __restrict__ eWih0, const float* __restrict__ eWhh0,
    const float* __restrict__ ebih0, const float* __restrict__ ebhh0,
    const float* __restrict__ eWih1, const float* __restrict__ eWhh1,
    const float* __restrict__ ebih1, const float* __restrict__ ebhh1,
    const float* __restrict__ dWih0, const float* __restrict__ dWhh0,
    const float* __restrict__ dbih0, const float* __restrict__ dbhh0,
    const float* __restrict__ dWih1, const float* __restrict__ dWhh1,
    const float* __restrict__ dbih1, const float* __restrict__ dbhh1,
    const float* __restrict__ fcW,  const float* __restrict__ fcb,
    float* __restrict__ ws)
{
    int idx = blockIdx.x * blockDim.x + threadIdx.x;
    if (idx >= WS_TOT) return;
    float outv;
    if (idx < OFF_FCW) {
        int off, nkc, which;
        if (idx < OFF_E1)      { off = OFF_E0; nkc = NKC0; which = 0; }
        else if (idx < OFF_D0) { off = OFF_E1; nkc = NKC1; which = 1; }
        else if (idx < OFF_D1) { off = OFF_D0; nkc = NKC0; which = 2; }
        else                   { off = OFF_D1; nkc = NKC1; which = 3; }
        int rel = idx - off;
        int w = rel & 3, lane = (rel >> 2) & 63;
        int rest = rel >> 8;
        int kc = rest % nkc, gt = rest / nkc;
        int gr = lane & 31;
        int q = gr >> 2, type = gr & 3;
        int j = type * 64 + gt * 8 + q;
        float sc = (type == 2) ? (2.0f * LOG2E) : (-LOG2E);
        union { f16 h2[2]; float f; } u_;
        #pragma unroll
        for (int hf = 0; hf < 2; ++hf) {
            int kl = (lane >> 5) * 8 + w * 2 + hf;
            float v = 0.0f;
            if (which == 0) {            // enc L0
                if (kc == 0) {
                    if (kl < IN_)      v = eWih0[j * IN_ + kl];
                    else if (kl == 5)  v = ebih0[j] + ebhh0[j];
                } else                   v = eWhh0[j * 64 + (kc - 1) * 16 + kl];
            } else if (which == 1) {     // enc L1
                if (kc < 4)            v = eWih1[j * 64 + kc * 16 + kl];
                else if (kc < 8)       v = eWhh1[j * 64 + (kc - 4) * 16 + kl];
                else if (kl == 0)      v = ebih1[j] + ebhh1[j];   // bias chunk
            } else if (which == 2) {     // dec L0
                if (kc == 0) {
                    if (kl == 0)       v = dWih0[j];
                    else if (kl == 5)  v = dbih0[j] + dbhh0[j];
                } else                   v = dWhh0[j * 64 + (kc - 1) * 16 + kl];
            } else {                     // dec L1
                if (kc < 4)            v = dWih1[j * 64 + kc * 16 + kl];
                else if (kc < 8)       v = dWhh1[j * 64 + (kc - 4) * 16 + kl];
                else if (kl == 0)      v = dbih1[j] + dbhh1[j];
            }
            u_.h2[hf] = (f16)(v * sc);
        }
        outv = u_.f;
    } else if (idx < OFF_FCB) {
        outv = fcW[idx - OFF_FCW];
    } else {
        outv = fcb[0];
    }
    ws[idx] = outv;
}

// LDS layouts (f16 element index). B-frag read: lane l -> hf = l>>5,
// col/row = rt*32 + (l&31); k = kc*16 + hf*8 + j.
__device__ __forceinline__ int xbi(int b, int pl, int hf, int row) {
    return ((((b * 2 + pl) * 2 + hf) * 64) + row) * 8;
}
__device__ __forceinline__ int hbi(int b, int pl, int kc, int hf, int row) {
    return (((((b * 2 + pl) * 4 + kc) * 2 + hf) * 64) + row) * 8;
}
#define XTOT  (2*2*2*64*8)     // 4096 f16 = 8 KB
#define HTOT  (2*2*4*2*64*8)   // 16384 f16 = 32 KB
#define HHALF (2*4*2*64*8)     // one buf = 8192 f16
#define PLSTR (4*2*64*8)       // pl stride within buf = 4096 f16

#define MFMA32(a,b,c) __builtin_amdgcn_mfma_f32_32x32x16_f16(a, b, c, 0, 0, 0)

__device__ __forceinline__ void stage_x5(f16* __restrict__ XB, int b, int r, const float* xv) {
    f16x8 ph = {}, pl_ = {}, zz = {};
    #pragma unroll
    for (int i = 0; i < IN_; ++i) {
        f16 hh = (f16)xv[i]; ph[i] = hh; pl_[i] = (f16)(xv[i] - (float)hh);
    }
    ph[5] = (f16)1.0f;          // bias slot (k=5)
    *(f16x8*)&XB[xbi(b,0,0,r)] = ph;
    *(f16x8*)&XB[xbi(b,0,1,r)] = zz;
    *(f16x8*)&XB[xbi(b,1,0,r)] = pl_;
    *(f16x8*)&XB[xbi(b,1,1,r)] = zz;
}
__device__ __forceinline__ void stage_x1(f16* __restrict__ XB, int b, int r, float v) {
    f16x8 ph = {}, pl_ = {}, zz = {};
    f16 hh = (f16)v; ph[0] = hh; pl_[0] = (f16)(v - (float)hh);
    ph[5] = (f16)1.0f;
    *(f16x8*)&XB[xbi(b,0,0,r)] = ph;
    *(f16x8*)&XB[xbi(b,0,1,r)] = zz;
    *(f16x8*)&XB[xbi(b,1,0,r)] = pl_;
    *(f16x8*)&XB[xbi(b,1,1,r)] = zz;
}

// activation+store for one bundle (unit qi of this wave's tile).
// acc regs 4qi..4qi+3 = gates i,f,g,o of unit u = gt*8 + 2*qi + hf, col = row.
__device__ __forceinline__ void act_store(
    float gi, float gf, float gg_, float go, float& c, int qi,
    int gt, int hf, int row, int b, f16* __restrict__ H, float* __restrict__ H1F)
{
    float ig = sig2(gi), fg = sig2(gf);
    float gg = tanh2(gg_), og = sig2(go);
    float cc = fmaf(fg, c, ig * gg);
    c = cc;
    float h = og * tanhc(cc);
    f16 hh = (f16)h, hl = (f16)(h - (float)hh);
    int u = gt * 8 + 2 * qi + hf;
    int base = hbi(b, 0, u >> 4, (u >> 3) & 1, row) + (u & 7);
    H[base] = hh;
    H[base + PLSTR] = hl;
    if (H1F) H1F[u * 65 + row] = h;
}

// ---- standalone layer 0 (prologue + decoder): z = W0 @ [x|h0_prev], bias in x k5
__device__ __forceinline__ void layer0_only(
    int pX, int pH0r, int pH0w, int gt, int hf, int row,
    const f16x8 (&wa0)[NKC0], float (&c0)[4],
    const f16* __restrict__ XB, f16* __restrict__ H0B)
{
    f32x16 z = {};
    #pragma unroll
    for (int kc = 0; kc < 4; ++kc) {
        f16x8 hh = *(const f16x8*)&H0B[hbi(pH0r,0,kc,hf,row)];
        f16x8 hl = *(const f16x8*)&H0B[hbi(pH0r,1,kc,hf,row)];
        z = MFMA32(wa0[1+kc], hh, z);
        z = MFMA32(wa0[1+kc], hl, z);
    }
    {
        f16x8 xh = *(const f16x8*)&XB[xbi(pX,0,hf,row)];
        f16x8 xl = *(const f16x8*)&XB[xbi(pX,1,hf,row)];
        z = MFMA32(wa0[0], xh, z);
        z = MFMA32(wa0[0], xl, z);
    }
    #pragma unroll
    for (int qi = 0; qi < 4; ++qi)
        act_store(z[4*qi], z[4*qi+1], z[4*qi+2], z[4*qi+3], c0[qi], qi,
                  gt, hf, row, pH0w, H0B, nullptr);
}

// ---- standalone layer 1 (epilogue + decoder): a = W1 @ [h0|h1_prev] + bias chunk
template<bool DEC>
__device__ __forceinline__ void layer1_only(
    int pH0, int pH1r, int pH1w, int gt, int hf, int row,
    const f16x8 (&wa1)[NKC1], f16x8 bvec, float (&c1)[4],
    const f16* __restrict__ H0B, f16* __restrict__ H1B, float* __restrict__ H1F)
{
    f32x16 a = {};
    a = MFMA32(wa1[8], bvec, a);            // bias (B one-hot at k0)
    #pragma unroll
    for (int kc = 0; kc < 4; ++kc) {
        f16x8 hh = *(const f16x8*)&H0B[hbi(pH0,0,kc,hf,row)];
        f16x8 hl = *(const f16x8*)&H0B[hbi(pH0,1,kc,hf,row)];
        a = MFMA32(wa1[kc], hh, a);
        a = MFMA32(wa1[kc], hl, a);
    }
    #pragma unroll
    for (int kc = 0; kc < 4; ++kc) {
        f16x8 gh = *(const f16x8*)&H1B[hbi(pH1r,0,kc,hf,row)];
        f16x8 gl = *(const f16x8*)&H1B[hbi(pH1r,1,kc,hf,row)];
        a = MFMA32(wa1[4+kc], gh, a);
        a = MFMA32(wa1[4+kc], gl, a);
    }
    #pragma unroll
    for (int qi = 0; qi < 4; ++qi)
        act_store(a[4*qi], a[4*qi+1], a[4*qi+2], a[4*qi+3], c1[qi], qi,
                  gt, hf, row, pH1w, H1B, DEC ? H1F : nullptr);
}

// ---- fused encoder phase t: {L1_t ; L0_{t+1}} — ONE barrier per timestep.
// h0_t frags read ONCE, shared by both chains. z-act bundles interleaved
// between the a-chain's h1 MFMA chunks (independent -> fills issue stream).
__device__ __forceinline__ void enc_phase(
    int p, int gt, int hf, int row,
    const f16x8 (&wa0)[NKC0], const f16x8 (&wa1)[NKC1], f16x8 bvec,
    float (&c0)[4], float (&c1)[4],
    const f16* __restrict__ XB, f16* __restrict__ H0B, f16* __restrict__ H1B)
{
    const int q = p ^ 1;
    f32x16 a = {};
    f32x16 z = {};
    a = MFMA32(wa1[8], bvec, a);            // L1 bias
    #pragma unroll
    for (int kc = 0; kc < 4; ++kc) {        // shared h0_t chunks
        f16x8 hh = *(const f16x8*)&H0B[hbi(p,0,kc,hf,row)];
        f16x8 hl = *(const f16x8*)&H0B[hbi(p,1,kc,hf,row)];
        a = MFMA32(wa1[kc], hh, a);
        a = MFMA32(wa1[kc], hl, a);
        z = MFMA32(wa0[1+kc], hh, z);
        z = MFMA32(wa0[1+kc], hl, z);
    }
    {                                        // x_{t+1} chunk -> z complete
        f16x8 xh = *(const f16x8*)&XB[xbi(q,0,hf,row)];
        f16x8 xl = *(const f16x8*)&XB[xbi(q,1,hf,row)];
        z = MFMA32(wa0[0], xh, z);
        z = MFMA32(wa0[0], xl, z);
    }
    #pragma unroll
    for (int kc = 0; kc < 4; ++kc) {        // h1_{t-1} chunks; z-acts interleave
        f16x8 gh = *(const f16x8*)&H1B[hbi(q,0,kc,hf,row)];
        f16x8 gl = *(const f16x8*)&H1B[hbi(q,1,kc,hf,row)];
        a = MFMA32(wa1[4+kc], gh, a);
        a = MFMA32(wa1[4+kc], gl, a);
        act_store(z[4*kc], z[4*kc+1], z[4*kc+2], z[4*kc+3], c0[kc], kc,
                  gt, hf, row, q, H0B, nullptr);
    }
    #pragma unroll
    for (int qi = 0; qi < 4; ++qi)
        act_store(a[4*qi], a[4*qi+1], a[4*qi+2], a[4*qi+3], c1[qi], qi,
                  gt, hf, row, p, H1B, nullptr);
}

// 1024 threads = 16 waves; wave = gt*2 + rt owns one 32-gate x 32-row tile of
// BOTH L1_t and L0_{t+1} (shared h0 frags). ROWS=64/block, grid=256 (1/CU).
// waves_per_eu(4,4): LDS (88.5 KB) caps the CU at ONE 16-wave block = 4
// waves/EU, so pin the allocator there -> 128-VGPR budget for the ~120-reg
// live set. R8 (no attribute) had the allocator target 8 waves/EU -> 64 regs
// -> 43 MB/dispatch scratch spill. R4 lesson still holds: 128 >= live set.
__global__ __launch_bounds__(1024)
__attribute__((amdgpu_waves_per_eu(4, 4)))
void lstm_kernel(
    const float* __restrict__ src, const float* __restrict__ ws,
    float* __restrict__ out)
{
    __shared__ __align__(16) f16 XB [XTOT];   // 8 KB
    __shared__ __align__(16) f16 H0B[HTOT];   // 32 KB
    __shared__ __align__(16) f16 H1B[HTOT];   // 32 KB
    __shared__ float H1F[64 * 65];            // 16.25 KB (decoder fc)
    __shared__ float FCW[64];

    const int tid  = threadIdx.x;
    const int lane = tid & 63;
    const int wave = __builtin_amdgcn_readfirstlane(tid >> 6);
    const int gt   = wave >> 1;
    const int rt   = wave & 1;
    const int hf   = lane >> 5;
    const int row  = rt * 32 + (lane & 31);
    const int rowBase = blockIdx.x * ROWS;

    float c0[4], c1[4];
    #pragma unroll
    for (int i = 0; i < 4; ++i) { c0[i] = 0.0f; c1[i] = 0.0f; }

    f16x8 wa0[NKC0], wa1[NKC1];
    f16x8 bvec = {};
    if (hf == 0) bvec[0] = (f16)1.0f;   // one-hot B for the bias chunk (k=0)

    auto ldw = [&](int off0, int off1) {
        #pragma unroll
        for (int kc = 0; kc < NKC0; ++kc)
            wa0[kc] = *(const f16x8*)(ws + off0 + ((gt * NKC0 + kc) * 64 + lane) * 4);
        #pragma unroll
        for (int kc = 0; kc < NKC1; ++kc)
            wa1[kc] = *(const f16x8*)(ws + off1 + ((gt * NKC1 + kc) * 64 + lane) * 4);
    };
    ldw(OFF_E0, OFF_E1);

    // zero parity-1 halves of H0B/H1B (h0_{-1} = h1_{-1} = 0)
    for (int i = tid; i < HHALF; i += 1024) { H0B[HHALF + i] = (f16)0; H1B[HHALF + i] = (f16)0; }
    if (tid < 64) FCW[tid] = ws[OFF_FCW + tid];
    const float fcbv = ws[OFF_FCB];

    const float* sp = src + (size_t)(rowBase + lane) * (S_ * IN_);
    __syncthreads();

    // stage x0 -> XB[0], x1 -> XB[1] (wave 15: lane = row, 64 rows)
    if (wave == 15) {
        float xv[IN_];
        #pragma unroll
        for (int i = 0; i < IN_; ++i) xv[i] = sp[i];
        stage_x5(XB, 0, lane, xv);
        #pragma unroll
        for (int i = 0; i < IN_; ++i) xv[i] = sp[IN_ + i];
        stage_x5(XB, 1, lane, xv);
    }
    __syncthreads();

    // prologue: L0_0 (reads XB[0], H0B[1](=0), writes H0B[0])
    layer0_only(0, 1, 0, gt, hf, row, wa0, c0, XB, H0B);
    __syncthreads();

    // ---------------- encoder: fused phases, ONE barrier per timestep ----------
    #pragma unroll 1
    for (int t = 0; t < S_ - 1; ++t) {
        const int p = t & 1;
        float xv[IN_];
        const bool pf = (wave == 15) && (t + 2 < S_);
        if (pf) {
            #pragma unroll
            for (int i = 0; i < IN_; ++i) xv[i] = sp[(t + 2) * IN_ + i];
        }
        enc_phase(p, gt, hf, row, wa0, wa1, bvec, c0, c1, XB, H0B, H1B);
        if (pf) stage_x5(XB, p, lane, xv);   // x_{t+2} -> XB[(t+2)&1] = XB[p]
        __syncthreads();
    }

    // epilogue: L1_{S-1} (reads H0B[1], H1B[0], writes H1B[1])
    layer1_only<false>(1, 0, 1, gt, hf, row, wa1, bvec, c1, H0B, H1B, H1F);
    __syncthreads();

    // ---------------- decoder ----------------
    ldw(OFF_D0, OFF_D1);
    if (wave == 15) stage_x1(XB, 0, lane, sp[(S_ - 1) * IN_ + 3]);   // dec_in0
    __syncthreads();

    #pragma unroll 1
    for (int t = 0; t < T_; ++t) {
        const int q = t & 1;
        layer0_only(q, q ^ 1, q, gt, hf, row, wa0, c0, XB, H0B);
        __syncthreads();
        layer1_only<true>(q, q ^ 1, q, gt, hf, row, wa1, bvec, c1, H0B, H1B, H1F);
        __syncthreads();
        if (wave == 0) {   // fc head: pred = fcW . h1_new + fcb  (lane = row)
            float pv = fcbv;
            #pragma unroll 8
            for (int k = 0; k < 64; ++k) pv = fmaf(FCW[k], H1F[k * 65 + lane], pv);
            out[(size_t)(rowBase + lane) * T_ + t] = pv;
            if (t + 1 < T_) stage_x1(XB, q ^ 1, lane, pv);
        }
        __syncthreads();
    }
}

extern "C" void kernel_launch(void* const* d_in, const int* in_sizes, int n_in,
                              void* d_out, int out_size, void* d_ws, size_t ws_size,
                              hipStream_t stream)
{
    const float* src = (const float*)d_in[0];
    float* ws  = (float*)d_ws;
    float* out = (float*)d_out;

    prep_kernel<<<(WS_TOT + 255) / 256, 256, 0, stream>>>(
        (const float*)d_in[1],  (const float*)d_in[2],
        (const float*)d_in[3],  (const float*)d_in[4],
        (const float*)d_in[5],  (const float*)d_in[6],
        (const float*)d_in[7],  (const float*)d_in[8],
        (const float*)d_in[9],  (const float*)d_in[10],
        (const float*)d_in[11], (const float*)d_in[12],
        (const float*)d_in[13], (const float*)d_in[14],
        (const float*)d_in[15], (const float*)d_in[16],
        (const float*)d_in[17], (const float*)d_in[18],
        ws);

    lstm_kernel<<<B_ / ROWS, 1024, 0, stream>>>(src, ws, out);
}